// Round 12
// baseline (698.071 us; speedup 1.0000x reference)
//
#include <hip/hip_runtime.h>
#include <hip/hip_bf16.h>

// GraphSAGE 4-layer forward.
// R2-R5: bf16 activations; MFMA GEMM; BN folded forward; binned CSR build.
// R6-R13: GEMM wall study -- six load/occupancy schedules all pin at ~72us
//     with A-stream = 51.2MB staged (hb+aggb). Slot-stats + 8-chunk pool won.
// R14: Y-SPACE RESTRUCTURE -- agg commutes with W-multiply:
//     agg(h)@Wn = agg(h@Wn). k_gemm2 computes Ys=h@(sc.Ws), Yn=h@(sc.Wn)
//     from ONE staged A-tile (8 gl_lds, 32KB LDS, 2x occupancy); k_aggfin
//     gathers Yn + adds Ys/beffS/cN + PReLU + stats + writes next hb.
//     Zero-degree handled exactly (cN added only when deg>0). bnfin absorbs
//     W-prescale + partial-zero (no per-layer memset).

#define EPS_BN 1e-5f
#define BSH 9                 // 512 nodes per bucket
#define BCHUNK 4096           // edges per k_bin block
#define PCAP 10240            // max edges per bucket for LDS staging (mean 8192)
#define AGG_BLOCKS 2048
#define NPSLOT 64             // stat slots (aggfin blocks >> 5)

typedef __attribute__((ext_vector_type(8))) short bf16x8;
typedef __attribute__((ext_vector_type(4))) float f32x4;
typedef __attribute__((address_space(1))) const void gconst_t;
typedef __attribute__((address_space(3))) void ldsv_t;

// ---------------- embedding gather -> bf16 h ---------------------------------
__global__ __launch_bounds__(256) void k_embed(const int* __restrict__ feat,
                                               const float* __restrict__ emb,
                                               __hip_bfloat162* __restrict__ hb2, int n) {
  int idx = blockIdx.x * 256 + threadIdx.x;   // one bf16x2 each
  if (idx < n * 64) {
    int i = idx >> 6, c2 = idx & 63;
    float2 v = ((const float2*)emb)[feat[i] * 64 + c2];
    hb2[idx] = __float22bfloat162_rn(v);
  }
}

// ---------------- W -> bf16, transposed: Wt[l][n][k] = W[l][k][n] ------------
__global__ __launch_bounds__(256) void k_wconv(const float* __restrict__ W,
                                               __hip_bfloat16* __restrict__ Wt, int total) {
  int idx = blockIdx.x * 256 + threadIdx.x;
  if (idx < total) {
    int l = idx >> 14, r = idx & 16383, nn = r >> 7, kk = r & 127;
    Wt[idx] = __float2bfloat16(W[(l << 14) + kk * 128 + nn]);
  }
}

// ---------------- per-graph node offsets via binary search (gid sorted) ------
__global__ void k_gcount(const int* __restrict__ gid, int* __restrict__ gcnt,
                         int* __restrict__ gstart, int n, int G) {
  int g = blockIdx.x * blockDim.x + threadIdx.x;
  if (g >= G) return;
  int lo0 = 0, hi = n;
  while (lo0 < hi) { int mid = (lo0 + hi) >> 1; if (gid[mid] < g) lo0 = mid + 1; else hi = mid; }
  int lo1 = lo0; hi = n;
  while (lo1 < hi) { int mid = (lo1 + hi) >> 1; if (gid[mid] < g + 1) lo1 = mid + 1; else hi = mid; }
  gstart[g] = lo0;
  gcnt[g] = lo1 - lo0;
}

// ---------------- bucket histogram over dst (LDS-staged) ---------------------
__global__ __launch_bounds__(256) void k_bhist(const int* __restrict__ dst,
                                               int* __restrict__ bktcnt, int m, int nbkt) {
  __shared__ int h[256];
  int t = threadIdx.x;
  h[t] = 0;
  __syncthreads();
#pragma unroll
  for (int k = 0; k < 4; ++k) {
    int idx = blockIdx.x * BCHUNK + k * 1024 + t * 4;
    if (idx + 4 <= m) {
      int4 d = *(const int4*)&dst[idx];
      atomicAdd(&h[d.x >> BSH], 1);
      atomicAdd(&h[d.y >> BSH], 1);
      atomicAdd(&h[d.z >> BSH], 1);
      atomicAdd(&h[d.w >> BSH], 1);
    } else {
      for (int e = idx; e < m && e < idx + 4; ++e) atomicAdd(&h[dst[e] >> BSH], 1);
    }
  }
  __syncthreads();
  for (int b = t; b < nbkt; b += 256)
    if (h[b]) atomicAdd(&bktcnt[b], h[b]);
}

// ---------------- scan bucket counts -> base & cursor ------------------------
__global__ void k_bscan(const int* __restrict__ bktcnt, int* __restrict__ bbase,
                        int* __restrict__ bcur, int m, int nbkt) {
  __shared__ int sh[256];
  int t = threadIdx.x;
  int v = (t < nbkt) ? bktcnt[t] : 0;
  sh[t] = v;
  __syncthreads();
  for (int o = 1; o < 256; o <<= 1) {
    int x = (t >= o) ? sh[t - o] : 0;
    __syncthreads();
    sh[t] += x;
    __syncthreads();
  }
  if (t < nbkt) { bbase[t] = sh[t] - v; bcur[t] = sh[t] - v; }
  if (t == 0) bbase[nbkt] = m;
}

// ---------------- bin edges by bucket (LDS counting sort, coalesced out) -----
__global__ __launch_bounds__(256) void k_bin(const int* __restrict__ src, const int* __restrict__ dst,
                                             int* __restrict__ bcur, uint2* __restrict__ binned,
                                             int m, int nbkt) {
  __shared__ uint2 st[BCHUNK];
  __shared__ int bcnt[256], boff[256], bres[256], wcur[256], ss[256];
  int t = threadIdx.x;
  int e0 = blockIdx.x * BCHUNK;
  int cn = min(BCHUNK, m - e0);
  int sv[16], dv[16];
  for (int b = t; b < 256; b += 256) bcnt[b] = 0;
  __syncthreads();
#pragma unroll
  for (int k = 0; k < 16; ++k) {
    int idx = e0 + k * 256 + t;
    if (idx < e0 + cn) {
      sv[k] = src[idx];
      dv[k] = dst[idx];
      atomicAdd(&bcnt[dv[k] >> BSH], 1);
    } else dv[k] = -1;
  }
  __syncthreads();
  int v = (t < nbkt) ? bcnt[t] : 0;
  ss[t] = v;
  __syncthreads();
  for (int o = 1; o < 256; o <<= 1) {
    int x = (t >= o) ? ss[t - o] : 0;
    __syncthreads();
    ss[t] += x;
    __syncthreads();
  }
  if (t < nbkt) {
    int ex = ss[t] - v;
    boff[t] = ex;
    wcur[t] = ex;
    if (v) bres[t] = atomicAdd(&bcur[t], v);
  }
  __syncthreads();
#pragma unroll
  for (int k = 0; k < 16; ++k) {
    if (dv[k] >= 0) {
      int b = dv[k] >> BSH;
      int p = atomicAdd(&wcur[b], 1);
      st[p] = make_uint2((unsigned)sv[k], (unsigned)dv[k]);
    }
  }
  __syncthreads();
  for (int j = t; j < cn; j += 256) {
    uint2 e = st[j];
    int b = (int)(e.y >> BSH);
    binned[(size_t)bres[b] + (j - boff[b])] = e;
  }
}

// ---------------- per-bucket node counts (LDS, coalesced cnt write) ----------
__global__ __launch_bounds__(256) void k_cnt(const uint2* __restrict__ binned,
                                             const int* __restrict__ bbase,
                                             int* __restrict__ cnt, int n) {
  __shared__ int h[512];
  int b = blockIdx.x, t = threadIdx.x;
  int base = b << BSH;
  int nn = min(512, n - base);
  h[t] = 0; h[t + 256] = 0;
  __syncthreads();
  int lo = bbase[b], hi = bbase[b + 1];
  for (int j = lo + t; j < hi; j += 256) atomicAdd(&h[(int)binned[j].y - base], 1);
  __syncthreads();
  if (t < nn) cnt[base + t] = h[t];
  if (t + 256 < nn) cnt[base + t + 256] = h[t + 256];
}

// ---------------- exclusive scan of cnt -> row_ptr (3 kernels) ---------------
__global__ __launch_bounds__(256) void k_scan1(const int* __restrict__ cnt,
                                               int* __restrict__ excl,
                                               int* __restrict__ blk_sums, int n) {
  __shared__ int sh[256];
  int t = threadIdx.x;
  int base = blockIdx.x * 1024 + t * 4;
  int4 v = {0, 0, 0, 0};
  if (base < n) v = *(const int4*)&cnt[base];
  int s = v.x + v.y + v.z + v.w;
  sh[t] = s;
  __syncthreads();
  for (int off = 1; off < 256; off <<= 1) {
    int x = (t >= off) ? sh[t - off] : 0;
    __syncthreads();
    sh[t] += x;
    __syncthreads();
  }
  int ex = sh[t] - s;
  if (t == 255) blk_sums[blockIdx.x] = sh[255];
  if (base < n) {
    excl[base]     = ex;
    excl[base + 1] = ex + v.x;
    excl[base + 2] = ex + v.x + v.y;
    excl[base + 3] = ex + v.x + v.y + v.z;
  }
}

__global__ void k_scan2(int* __restrict__ bs, int nb) {
  __shared__ int sh[128];
  int t = threadIdx.x;
  int v = (t < nb) ? bs[t] : 0;
  sh[t] = v;
  __syncthreads();
  for (int off = 1; off < 128; off <<= 1) {
    int x = (t >= off) ? sh[t - off] : 0;
    __syncthreads();
    sh[t] += x;
    __syncthreads();
  }
  if (t < nb) bs[t] = sh[t] - v;
}

__global__ __launch_bounds__(256) void k_scan3(int* __restrict__ rp, const int* __restrict__ bs,
                                               const int* __restrict__ cnt, int* __restrict__ cursor,
                                               float* __restrict__ deg, int n, int ne) {
  int i = blockIdx.x * 256 + threadIdx.x;
  if (i < n) {
    int r = rp[i] + bs[i >> 10];
    rp[i] = r;
    cursor[i] = r;
    int c = cnt[i];
    deg[i] = (float)(c > 0 ? c : 1);
  }
  if (i == 0) rp[n] = ne;
}

// ---------------- place edges into CSR (per-bucket LDS sort, coalesced) ------
__global__ __launch_bounds__(256) void k_place(const uint2* __restrict__ binned,
                                               const int* __restrict__ bbase,
                                               const int* __restrict__ rp,
                                               int* __restrict__ cursor,
                                               int* __restrict__ csr_src, int n) {
  int b = blockIdx.x, t = threadIdx.x;
  int base = b << BSH;
  int lo = bbase[b], hi = bbase[b + 1], m = hi - lo;
  if (m <= 0) return;
  if (m > PCAP) {                          // fallback: global-atomic scatter
    for (int j = lo + t; j < hi; j += 256) {
      uint2 e = binned[j];
      int p = atomicAdd(&cursor[(int)e.y], 1);
      csr_src[p] = (int)e.x;
    }
    return;
  }
  __shared__ int h[512], loff[512], wc[512], ss[256];
  __shared__ int stage[PCAP];
  h[t] = 0; h[t + 256] = 0;
  __syncthreads();
  for (int j = lo + t; j < hi; j += 256) atomicAdd(&h[(int)binned[j].y - base], 1);
  __syncthreads();
  int a0 = h[2 * t], a1 = h[2 * t + 1];
  int s = a0 + a1;
  ss[t] = s;
  __syncthreads();
  for (int o = 1; o < 256; o <<= 1) {
    int x = (t >= o) ? ss[t - o] : 0;
    __syncthreads();
    ss[t] += x;
    __syncthreads();
  }
  int ex = ss[t] - s;
  loff[2 * t] = ex; loff[2 * t + 1] = ex + a0;
  wc[2 * t] = ex;   wc[2 * t + 1] = ex + a0;
  __syncthreads();
  for (int j = lo + t; j < hi; j += 256) {
    uint2 e = binned[j];
    int p = atomicAdd(&wc[(int)e.y - base], 1);
    stage[p] = (int)e.x;
  }
  __syncthreads();
  int cb = rp[base];
  for (int j = t; j < m; j += 256) csr_src[cb + j] = stage[j];
}

// ----- init: identity BN, layer-0 beffS=b0, cN0=0, copy W0 -> Ws2/Wn2 --------
__global__ __launch_bounds__(256) void k_prep(const float* __restrict__ b0,
                                              float* __restrict__ ss0,
                                              float* __restrict__ beffS0,
                                              float* __restrict__ cN0,
                                              const uint4* __restrict__ Wst0,
                                              const uint4* __restrict__ Wnt0,
                                              uint4* __restrict__ Ws2,
                                              uint4* __restrict__ Wn2) {
  int id = blockIdx.x * 256 + threadIdx.x;     // 0..4095
  if (id < 128) {
    ss0[id] = 1.f; ss0[128 + id] = 0.f;
    beffS0[id] = b0[id]; cN0[id] = 0.f;
  }
  int half = id >> 11, ch = id & 2047;         // 2048 uint4 chunks each
  if (half) Wn2[ch] = Wnt0[ch]; else Ws2[ch] = Wst0[ch];
}

// ------- k_gemm2: Ys = hb@Ws2, Yn = hb@Wn2 (one staged A-tile) ---------------
// R9-style async global_load_lds staging (pre-swizzled source), 32KB LDS.
// acc reused across the two B matrices (s=0 -> Ys store, s=1 -> Yn store).
__global__ __launch_bounds__(256) void k_gemm2(
    const __hip_bfloat16* __restrict__ hb,
    const __hip_bfloat16* __restrict__ Wst2, const __hip_bfloat16* __restrict__ Wnt2,
    __hip_bfloat16* __restrict__ Ys, __hip_bfloat16* __restrict__ Yn, int n) {
  __shared__ short Ah[128 * 128];
  int t = threadIdx.x;
  int row0 = blockIdx.x * 128;
  int w = t >> 6, lane = t & 63;

  // ---- async stage: 8 rounds, 16B/lane, LDS dest linear ----
#pragma unroll
  for (int rd = 0; rd < 8; ++rd) {
    int Gq = rd * 256 + w * 64 + lane;       // granule id 0..2047 (16B each)
    int r = Gq >> 4;                          // local row 0..127
    int gq = (Gq & 15) ^ (r & 7);             // pre-swizzled source granule
    int grow = row0 + r;
    grow = grow < n ? grow : n - 1;           // clamp: garbage rows never used
    const __hip_bfloat16* gs = hb + (size_t)grow * 128 + gq * 8;
    __builtin_amdgcn_global_load_lds((gconst_t*)gs,
        (ldsv_t*)&Ah[(rd * 256 + w * 64) * 8], 16, 0, 0);
  }
  asm volatile("s_waitcnt vmcnt(0)" ::: "memory");
  __syncthreads();

  int lr16 = lane & 15, hi = lane >> 4;
  const __hip_bfloat16* Bt[2] = {Wst2, Wnt2};
  __hip_bfloat16* Ot[2] = {Ys, Yn};
#pragma unroll
  for (int s = 0; s < 2; ++s) {
    const __hip_bfloat16* B = Bt[s];
    f32x4 acc[2][8];
#pragma unroll
    for (int fm = 0; fm < 2; ++fm)
#pragma unroll
      for (int fn = 0; fn < 8; ++fn) acc[fm][fn] = (f32x4){0.f, 0.f, 0.f, 0.f};
#pragma unroll
    for (int ks = 0; ks < 4; ++ks) {
      bf16x8 af[2], bfr[8];
#pragma unroll
      for (int fm = 0; fm < 2; ++fm) {
        int rl = w * 32 + fm * 16 + lr16;
        int gq = (ks * 4 + hi) ^ (lr16 & 7);
        af[fm] = *(const bf16x8*)&Ah[rl * 128 + gq * 8];
      }
#pragma unroll
      for (int fn = 0; fn < 8; ++fn)
        bfr[fn] = *(const bf16x8*)(B + (size_t)(fn * 16 + lr16) * 128 + ks * 32 + hi * 8);
#pragma unroll
      for (int fm = 0; fm < 2; ++fm)
#pragma unroll
        for (int fn = 0; fn < 8; ++fn)
          acc[fm][fn] = __builtin_amdgcn_mfma_f32_16x16x32_bf16(af[fm], bfr[fn], acc[fm][fn], 0, 0, 0);
    }
    // store this output (C/D: col = lane&15, row = 4*(lane>>4)+reg  [m89])
    __hip_bfloat16* O = Ot[s];
#pragma unroll
    for (int fm = 0; fm < 2; ++fm) {
      int rbase = row0 + w * 32 + fm * 16 + hi * 4;
#pragma unroll
      for (int fn = 0; fn < 8; ++fn) {
        int col = fn * 16 + lr16;
#pragma unroll
        for (int r = 0; r < 4; ++r) {
          int grow = rbase + r;
          if (grow < n) O[(size_t)grow * 128 + col] = __float2bfloat16(acc[fm][fn][r]);
        }
      }
    }
  }
}

// ------- k_aggfin: rst = PReLU(Ys + beffS + [deg>0: mean(Yn) + cN]) ----------
// One wave per node (4x16-lane groups, 8 edges in flight); writes next hb,
// accumulates BN stats into NPSLOT global slots.
__device__ __forceinline__ void acc8(float* a, uint4 v) {
  float2 f;
  f = __bfloat1622float2(*(const __hip_bfloat162*)&v.x); a[0] += f.x; a[1] += f.y;
  f = __bfloat1622float2(*(const __hip_bfloat162*)&v.y); a[2] += f.x; a[3] += f.y;
  f = __bfloat1622float2(*(const __hip_bfloat162*)&v.z); a[4] += f.x; a[5] += f.y;
  f = __bfloat1622float2(*(const __hip_bfloat162*)&v.w); a[6] += f.x; a[7] += f.y;
}

__global__ __launch_bounds__(256) void k_aggfin(
    const uint4* __restrict__ yn4, const int* __restrict__ rp,
    const int* __restrict__ csr_src, const float* __restrict__ deg,
    const uint4* __restrict__ ys4,
    const float* __restrict__ beffS, const float* __restrict__ cN,
    const float* __restrict__ pw,
    uint4* __restrict__ hbn4, float* __restrict__ partial, int n) {
  __shared__ float ls[128], lq[128];
  int t = threadIdx.x;
  int lane = t & 63, wid = t >> 6;
  int g = lane >> 4, lr = lane & 15;
  if (t < 128) { ls[t] = 0.f; lq[t] = 0.f; }
  __syncthreads();

  float bS[8], cn8[8], pw8[8], sacc[8], qacc[8];
#pragma unroll
  for (int c = 0; c < 8; ++c) {
    bS[c] = beffS[lr * 8 + c];
    cn8[c] = cN[lr * 8 + c];
    pw8[c] = pw[lr * 8 + c];
    sacc[c] = 0.f; qacc[c] = 0.f;
  }

  for (int i = blockIdx.x * 4 + wid; i < n; i += gridDim.x * 4) {
    int beg = rp[i], end = rp[i + 1];
    float a[8];
#pragma unroll
    for (int c = 0; c < 8; ++c) a[c] = 0.f;
    int e = beg;
    for (; e + 8 <= end; e += 8) {        // 8 edges per wave-iteration
      int s0 = csr_src[e + g];
      int s1 = csr_src[e + 4 + g];
      uint4 v0 = yn4[(size_t)s0 * 16 + lr];
      uint4 v1 = yn4[(size_t)s1 * 16 + lr];
      acc8(a, v0);
      acc8(a, v1);
    }
    for (; e + g < end; e += 4) {         // predicated 4-edge tail
      int s = csr_src[e + g];
      uint4 v = yn4[(size_t)s * 16 + lr];
      acc8(a, v);
    }
#pragma unroll
    for (int c = 0; c < 8; ++c) {         // combine the 4 groups
      a[c] += __shfl_xor(a[c], 16, 64);
      a[c] += __shfl_xor(a[c], 32, 64);
    }
    if (g == 0) {
      uint4 ysv = ys4[(size_t)i * 16 + lr];
      float y[8];
      float2 f;
      f = __bfloat1622float2(*(const __hip_bfloat162*)&ysv.x); y[0] = f.x; y[1] = f.y;
      f = __bfloat1622float2(*(const __hip_bfloat162*)&ysv.y); y[2] = f.x; y[3] = f.y;
      f = __bfloat1622float2(*(const __hip_bfloat162*)&ysv.z); y[4] = f.x; y[5] = f.y;
      f = __bfloat1622float2(*(const __hip_bfloat162*)&ysv.w); y[6] = f.x; y[7] = f.y;
      float invd = 1.0f / deg[i];
      bool has = (beg < end);
      float v[8];
#pragma unroll
      for (int c = 0; c < 8; ++c) {
        float x = y[c] + bS[c];
        if (has) x += a[c] * invd + cn8[c];
        x = x > 0.f ? x : pw8[c] * x;
        sacc[c] += x; qacc[c] += x * x;
        v[c] = x;
      }
      __hip_bfloat162 p0 = __float22bfloat162_rn(make_float2(v[0], v[1]));
      __hip_bfloat162 p1 = __float22bfloat162_rn(make_float2(v[2], v[3]));
      __hip_bfloat162 p2 = __float22bfloat162_rn(make_float2(v[4], v[5]));
      __hip_bfloat162 p3 = __float22bfloat162_rn(make_float2(v[6], v[7]));
      uint4 o;
      o.x = *(unsigned int*)&p0; o.y = *(unsigned int*)&p1;
      o.z = *(unsigned int*)&p2; o.w = *(unsigned int*)&p3;
      hbn4[(size_t)i * 16 + lr] = o;
    }
  }
  if (g == 0) {
#pragma unroll
    for (int c = 0; c < 8; ++c) {
      atomicAdd(&ls[lr * 8 + c], sacc[c]);
      atomicAdd(&lq[lr * 8 + c], qacc[c]);
    }
  }
  __syncthreads();
  if (t < 128) {
    float* pp = partial + (size_t)(blockIdx.x >> 5) * 256;
    atomicAdd(&pp[t], ls[t]);
    atomicAdd(&pp[128 + t], lq[t]);
  }
}

// ---- bnfin: stats -> BN affine; next-layer beffS/cN; W prescale; zero partial
__global__ __launch_bounds__(1024) void k_bnfin(float* __restrict__ partial, int nb,
                                                const float* __restrict__ gamma,
                                                const float* __restrict__ beta,
                                                float* __restrict__ ss,
                                                const float* __restrict__ bias_next,
                                                const float* __restrict__ Wsf_next,
                                                const float* __restrict__ Wnf_next,
                                                const __hip_bfloat16* __restrict__ Wst_next,
                                                const __hip_bfloat16* __restrict__ Wnt_next,
                                                __hip_bfloat16* __restrict__ Ws2,
                                                __hip_bfloat16* __restrict__ Wn2,
                                                float* __restrict__ beffS_next,
                                                float* __restrict__ cN_next,
                                                int has_next, int n) {
  __shared__ float red[4][256];
  __shared__ float shv[128], scv[128];
  __shared__ float bredS[8][128], bredN[8][128];
  int t = threadIdx.x, c = t & 255, part = t >> 8;
  float s = 0.f;
  for (int b = part; b < nb; b += 4) s += partial[(size_t)b * 256 + c];
  red[part][c] = s;
  __syncthreads();
  if (part == 0) red[0][c] = red[0][c] + red[1][c] + red[2][c] + red[3][c];
  __syncthreads();
  if (t < 128) {
    float inv_n = 1.0f / (float)n;
    float mu = red[0][t] * inv_n;
    float var = red[0][128 + t] * inv_n - mu * mu;
    float sc = rsqrtf(var + EPS_BN) * gamma[t];
    float sh = beta[t] - mu * sc;
    ss[t] = sc;
    ss[128 + t] = sh;
    shv[t] = sh;
    scv[t] = sc;
  }
  __syncthreads();
  if (has_next) {
    int cc = t & 127, kg = t >> 7;       // 8 k-groups x 128 channels
    float aS = 0.f, aN = 0.f;
#pragma unroll
    for (int k = kg * 16; k < kg * 16 + 16; ++k) {
      float sh = shv[k];
      aS += sh * Wsf_next[k * 128 + cc];
      aN += sh * Wnf_next[k * 128 + cc];
    }
    bredS[kg][cc] = aS;
    bredN[kg][cc] = aN;
    __syncthreads();
    if (t < 128) {
      float rS = bias_next[t], rN = 0.f;
#pragma unroll
      for (int kg2 = 0; kg2 < 8; ++kg2) { rS += bredS[kg2][t]; rN += bredN[kg2][t]; }
      beffS_next[t] = rS;
      cN_next[t] = rN;
    }
    // prescale next-layer Wt by sc[k]  (Wt layout [n][k], k = i & 127)
    for (int i = t; i < 16384; i += 1024) {
      float scf = scv[i & 127];
      Ws2[i] = __float2bfloat16(__bfloat162float(Wst_next[i]) * scf);
      Wn2[i] = __float2bfloat16(__bfloat162float(Wnt_next[i]) * scf);
    }
  }
  // zero partial for next layer's aggfin
  for (int i = t; i < nb * 256; i += 1024) partial[i] = 0.f;
}

// ------------- per-graph pool of raw rst (bf16): 8 chunks per graph ----------
__global__ __launch_bounds__(256) void k_pool(const uint4* __restrict__ hb4,
                                              const int* __restrict__ gstart,
                                              const int* __restrict__ gcnt,
                                              float* __restrict__ out, int l) {
  __shared__ float red[4][128];
  int g = blockIdx.x >> 3, c = blockIdx.x & 7;
  int len = gcnt[g];
  int i0 = gstart[g] + ((len * c) >> 3);
  int i1 = gstart[g] + ((len * (c + 1)) >> 3);
  if (i0 >= i1) return;
  int t = threadIdx.x, w = t >> 6, lane = t & 63;
  int gi = lane >> 4, lr = lane & 15;
  float a[8];
#pragma unroll
  for (int cc = 0; cc < 8; ++cc) a[cc] = 0.f;
#pragma unroll 2
  for (int r = i0 + w * 4 + gi; r < i1; r += 16) {   // 16 rows in flight
    uint4 v = hb4[(size_t)r * 16 + lr];
    acc8(a, v);
  }
#pragma unroll
  for (int cc = 0; cc < 8; ++cc) {                   // combine 4 groups in wave
    a[cc] += __shfl_xor(a[cc], 16, 64);
    a[cc] += __shfl_xor(a[cc], 32, 64);
  }
  if (gi == 0) {
#pragma unroll
    for (int cc = 0; cc < 8; ++cc) red[w][lr * 8 + cc] = a[cc];
  }
  __syncthreads();
  if (t < 128)
    atomicAdd(&out[(size_t)g * 512 + l * 128 + t],
              red[0][t] + red[1][t] + red[2][t] + red[3][t]);
}

// ------------- finalize: mean + BN affine per layer section ------------------
__global__ __launch_bounds__(256) void k_div(float* __restrict__ out, const int* __restrict__ gcnt,
                                             const float* __restrict__ ssbuf, int m) {
  int i = blockIdx.x * 256 + threadIdx.x;
  if (i < m) {
    int g = i >> 9;
    int lc = i & 511;
    int l = lc >> 7, c = lc & 127;
    const float* ss = ssbuf + (l + 1) * 256;
    int cn = gcnt[g];
    out[i] = (cn > 0) ? (out[i] / (float)cn) * ss[c] + ss[128 + c] : 0.f;
  }
}

extern "C" void kernel_launch(void* const* d_in, const int* in_sizes, int n_in,
                              void* d_out, int out_size, void* d_ws, size_t ws_size,
                              hipStream_t stream) {
  const int*   in_feat = (const int*)d_in[0];
  const int*   src     = (const int*)d_in[1];
  const int*   dst     = (const int*)d_in[2];
  const int*   gid     = (const int*)d_in[3];
  const float* emb     = (const float*)d_in[4];
  const float* Wself   = (const float*)d_in[5];
  const float* Wneigh  = (const float*)d_in[6];
  const float* bvec    = (const float*)d_in[7];
  const float* gamma   = (const float*)d_in[8];
  const float* beta    = (const float*)d_in[9];
  const float* prelu   = (const float*)d_in[10];
  const int N = in_sizes[0];
  const int E = in_sizes[1];
  const int G = out_size / 512;
  float* out = (float*)d_out;
  const int NB = (N + 127) / 128;          // gemm blocks
  const int NBKT = (N + 511) >> BSH;       // buckets (<=256 for N<=128K)

  char* p = (char*)d_ws;
  size_t off = 0;
  auto take = [&](size_t bytes) { void* r = p + off; off += (bytes + 255) & ~(size_t)255; return r; };
  __hip_bfloat16* hb0   = (__hip_bfloat16*)take((size_t)N * 128 * 2);
  __hip_bfloat16* hb1   = (__hip_bfloat16*)take((size_t)N * 128 * 2);
  __hip_bfloat16* Ysb   = (__hip_bfloat16*)take((size_t)N * 128 * 2);
  __hip_bfloat16* Ynb   = (__hip_bfloat16*)take((size_t)N * 128 * 2);
  __hip_bfloat16* Wst   = (__hip_bfloat16*)take((size_t)4 * 128 * 128 * 2);
  __hip_bfloat16* Wnt   = (__hip_bfloat16*)take((size_t)4 * 128 * 128 * 2);
  __hip_bfloat16* Wst2  = (__hip_bfloat16*)take((size_t)128 * 128 * 2);
  __hip_bfloat16* Wnt2  = (__hip_bfloat16*)take((size_t)128 * 128 * 2);
  float* partial        = (float*)take((size_t)NPSLOT * 256 * 4);
  float* ssbuf          = (float*)take((size_t)5 * 256 * 4);  // [l][sc|sh], l=0 identity
  float* beffS          = (float*)take((size_t)4 * 128 * 4);
  float* cNb            = (float*)take((size_t)4 * 128 * 4);
  uint2* binned  = (uint2*)take((size_t)E * 8);
  int*   csr_src = (int*)take((size_t)E * 4);
  int*   cnt     = (int*)take((size_t)N * 4);
  int*   rp      = (int*)take((size_t)(N + 1) * 4);
  int*   cursor  = (int*)take((size_t)N * 4);
  float* deg     = (float*)take((size_t)N * 4);
  int*   bs      = (int*)take(512);
  int*   gcnt    = (int*)take((size_t)G * 4);
  int*   gstart  = (int*)take((size_t)G * 4);
  int*   bktcnt  = (int*)take((size_t)NBKT * 4);
  int*   bbase   = (int*)take((size_t)(NBKT + 1) * 4);
  int*   bcur    = (int*)take((size_t)NBKT * 4);
  if (off > ws_size) return;

  hipMemsetAsync(bktcnt, 0, (size_t)NBKT * 4, stream);
  hipMemsetAsync(partial, 0, (size_t)NPSLOT * 256 * 4, stream);
  hipMemsetAsync(d_out, 0, (size_t)out_size * 4, stream);

  k_embed<<<(N * 64 + 255) / 256, 256, 0, stream>>>(in_feat, emb, (__hip_bfloat162*)hb0, N);
  k_wconv<<<(4 * 128 * 128 + 255) / 256, 256, 0, stream>>>(Wself, Wst, 4 * 128 * 128);
  k_wconv<<<(4 * 128 * 128 + 255) / 256, 256, 0, stream>>>(Wneigh, Wnt, 4 * 128 * 128);
  k_gcount<<<1, 128, 0, stream>>>(gid, gcnt, gstart, N, G);

  int nbb = (E + BCHUNK - 1) / BCHUNK;
  k_bhist<<<nbb, 256, 0, stream>>>(dst, bktcnt, E, NBKT);
  k_bscan<<<1, 256, 0, stream>>>(bktcnt, bbase, bcur, E, NBKT);
  k_bin<<<nbb, 256, 0, stream>>>(src, dst, bcur, binned, E, NBKT);
  k_cnt<<<NBKT, 256, 0, stream>>>(binned, bbase, cnt, N);
  int nsb = (N + 1023) / 1024;
  k_scan1<<<nsb, 256, 0, stream>>>(cnt, rp, bs, N);
  k_scan2<<<1, 128, 0, stream>>>(bs, nsb);
  k_scan3<<<(N + 255) / 256, 256, 0, stream>>>(rp, bs, cnt, cursor, deg, N, E);
  k_place<<<NBKT, 256, 0, stream>>>(binned, bbase, rp, cursor, csr_src, N);
  k_prep<<<16, 256, 0, stream>>>(bvec, ssbuf, beffS, cNb,
                                 (const uint4*)Wst, (const uint4*)Wnt,
                                 (uint4*)Wst2, (uint4*)Wnt2);

  __hip_bfloat16* bufs[2] = {hb0, hb1};
  for (int l = 0; l < 4; ++l) {
    __hip_bfloat16* hin  = bufs[l & 1];
    __hip_bfloat16* hout = bufs[(l + 1) & 1];
    k_gemm2<<<NB, 256, 0, stream>>>(hin, Wst2, Wnt2, Ysb, Ynb, N);
    k_aggfin<<<AGG_BLOCKS, 256, 0, stream>>>((const uint4*)Ynb, rp, csr_src, deg,
                                             (const uint4*)Ysb,
                                             beffS + l * 128, cNb + l * 128,
                                             prelu + l * 128,
                                             (uint4*)hout, partial, N);
    k_bnfin<<<1, 1024, 0, stream>>>(partial, NPSLOT, gamma + l * 128, beta + l * 128,
                                    ssbuf + (l + 1) * 256,
                                    bvec + ((l + 1) & 3) * 128,
                                    Wself + ((l + 1) & 3) * 16384,
                                    Wneigh + ((l + 1) & 3) * 16384,
                                    Wst + ((l + 1) & 3) * 16384,
                                    Wnt + ((l + 1) & 3) * 16384,
                                    Wst2, Wnt2,
                                    beffS + ((l + 1) & 3) * 128,
                                    cNb + ((l + 1) & 3) * 128,
                                    (l < 3) ? 1 : 0, N);
    k_pool<<<G * 8, 256, 0, stream>>>((const uint4*)hout, gstart, gcnt, out, l);
  }
  k_div<<<(out_size + 255) / 256, 256, 0, stream>>>(out, gcnt, ssbuf, out_size);
}

// Round 13
// 596.606 us; speedup vs baseline: 1.1701x; 1.1701x over previous
//
#include <hip/hip_runtime.h>
#include <hip/hip_bf16.h>

// GraphSAGE 4-layer forward.
// R2-R5: bf16 activations; MFMA GEMM; BN folded forward; binned CSR build.
// R6-R13: GEMM wall study -- staging rate pins at ~700 GB/s regardless of
//     schedule; time = staged_bytes / 700GB/s (confirmed by R14).
// R14: Y-space restructure (agg commutes with W): gemm2 stages ONE tile
//     (~38us), but aggfin (gather+finish fused) regressed to 93us.
// R15: un-fuse -- pure gather k_agg (Yn -> aggY, aliases dead hin buffer);
//     finish fused into the pool kernel (k_finpool): streams Ys+aggY,
//     computes PReLU'd rst, writes next hb, and one block-level reduction
//     feeds BOTH per-graph pool and BN stats (rows are graph-sorted).

#define EPS_BN 1e-5f
#define BSH 9                 // 512 nodes per bucket
#define BCHUNK 4096           // edges per k_bin block
#define PCAP 10240            // max edges per bucket for LDS staging (mean 8192)
#define AGG_BLOCKS 2048

typedef __attribute__((ext_vector_type(8))) short bf16x8;
typedef __attribute__((ext_vector_type(4))) float f32x4;
typedef __attribute__((address_space(1))) const void gconst_t;
typedef __attribute__((address_space(3))) void ldsv_t;

// ---------------- embedding gather -> bf16 h ---------------------------------
__global__ __launch_bounds__(256) void k_embed(const int* __restrict__ feat,
                                               const float* __restrict__ emb,
                                               __hip_bfloat162* __restrict__ hb2, int n) {
  int idx = blockIdx.x * 256 + threadIdx.x;   // one bf16x2 each
  if (idx < n * 64) {
    int i = idx >> 6, c2 = idx & 63;
    float2 v = ((const float2*)emb)[feat[i] * 64 + c2];
    hb2[idx] = __float22bfloat162_rn(v);
  }
}

// ---------------- W -> bf16, transposed: Wt[l][n][k] = W[l][k][n] ------------
__global__ __launch_bounds__(256) void k_wconv(const float* __restrict__ W,
                                               __hip_bfloat16* __restrict__ Wt, int total) {
  int idx = blockIdx.x * 256 + threadIdx.x;
  if (idx < total) {
    int l = idx >> 14, r = idx & 16383, nn = r >> 7, kk = r & 127;
    Wt[idx] = __float2bfloat16(W[(l << 14) + kk * 128 + nn]);
  }
}

// ---------------- per-graph node offsets via binary search (gid sorted) ------
__global__ void k_gcount(const int* __restrict__ gid, int* __restrict__ gcnt,
                         int* __restrict__ gstart, int n, int G) {
  int g = blockIdx.x * blockDim.x + threadIdx.x;
  if (g >= G) return;
  int lo0 = 0, hi = n;
  while (lo0 < hi) { int mid = (lo0 + hi) >> 1; if (gid[mid] < g) lo0 = mid + 1; else hi = mid; }
  int lo1 = lo0; hi = n;
  while (lo1 < hi) { int mid = (lo1 + hi) >> 1; if (gid[mid] < g + 1) lo1 = mid + 1; else hi = mid; }
  gstart[g] = lo0;
  gcnt[g] = lo1 - lo0;
}

// ---------------- bucket histogram over dst (LDS-staged) ---------------------
__global__ __launch_bounds__(256) void k_bhist(const int* __restrict__ dst,
                                               int* __restrict__ bktcnt, int m, int nbkt) {
  __shared__ int h[256];
  int t = threadIdx.x;
  h[t] = 0;
  __syncthreads();
#pragma unroll
  for (int k = 0; k < 4; ++k) {
    int idx = blockIdx.x * BCHUNK + k * 1024 + t * 4;
    if (idx + 4 <= m) {
      int4 d = *(const int4*)&dst[idx];
      atomicAdd(&h[d.x >> BSH], 1);
      atomicAdd(&h[d.y >> BSH], 1);
      atomicAdd(&h[d.z >> BSH], 1);
      atomicAdd(&h[d.w >> BSH], 1);
    } else {
      for (int e = idx; e < m && e < idx + 4; ++e) atomicAdd(&h[dst[e] >> BSH], 1);
    }
  }
  __syncthreads();
  for (int b = t; b < nbkt; b += 256)
    if (h[b]) atomicAdd(&bktcnt[b], h[b]);
}

// ---------------- scan bucket counts -> base & cursor ------------------------
__global__ void k_bscan(const int* __restrict__ bktcnt, int* __restrict__ bbase,
                        int* __restrict__ bcur, int m, int nbkt) {
  __shared__ int sh[256];
  int t = threadIdx.x;
  int v = (t < nbkt) ? bktcnt[t] : 0;
  sh[t] = v;
  __syncthreads();
  for (int o = 1; o < 256; o <<= 1) {
    int x = (t >= o) ? sh[t - o] : 0;
    __syncthreads();
    sh[t] += x;
    __syncthreads();
  }
  if (t < nbkt) { bbase[t] = sh[t] - v; bcur[t] = sh[t] - v; }
  if (t == 0) bbase[nbkt] = m;
}

// ---------------- bin edges by bucket (LDS counting sort, coalesced out) -----
__global__ __launch_bounds__(256) void k_bin(const int* __restrict__ src, const int* __restrict__ dst,
                                             int* __restrict__ bcur, uint2* __restrict__ binned,
                                             int m, int nbkt) {
  __shared__ uint2 st[BCHUNK];
  __shared__ int bcnt[256], boff[256], bres[256], wcur[256], ss[256];
  int t = threadIdx.x;
  int e0 = blockIdx.x * BCHUNK;
  int cn = min(BCHUNK, m - e0);
  int sv[16], dv[16];
  for (int b = t; b < 256; b += 256) bcnt[b] = 0;
  __syncthreads();
#pragma unroll
  for (int k = 0; k < 16; ++k) {
    int idx = e0 + k * 256 + t;
    if (idx < e0 + cn) {
      sv[k] = src[idx];
      dv[k] = dst[idx];
      atomicAdd(&bcnt[dv[k] >> BSH], 1);
    } else dv[k] = -1;
  }
  __syncthreads();
  int v = (t < nbkt) ? bcnt[t] : 0;
  ss[t] = v;
  __syncthreads();
  for (int o = 1; o < 256; o <<= 1) {
    int x = (t >= o) ? ss[t - o] : 0;
    __syncthreads();
    ss[t] += x;
    __syncthreads();
  }
  if (t < nbkt) {
    int ex = ss[t] - v;
    boff[t] = ex;
    wcur[t] = ex;
    if (v) bres[t] = atomicAdd(&bcur[t], v);
  }
  __syncthreads();
#pragma unroll
  for (int k = 0; k < 16; ++k) {
    if (dv[k] >= 0) {
      int b = dv[k] >> BSH;
      int p = atomicAdd(&wcur[b], 1);
      st[p] = make_uint2((unsigned)sv[k], (unsigned)dv[k]);
    }
  }
  __syncthreads();
  for (int j = t; j < cn; j += 256) {
    uint2 e = st[j];
    int b = (int)(e.y >> BSH);
    binned[(size_t)bres[b] + (j - boff[b])] = e;
  }
}

// ---------------- per-bucket node counts (LDS, coalesced cnt write) ----------
__global__ __launch_bounds__(256) void k_cnt(const uint2* __restrict__ binned,
                                             const int* __restrict__ bbase,
                                             int* __restrict__ cnt, int n) {
  __shared__ int h[512];
  int b = blockIdx.x, t = threadIdx.x;
  int base = b << BSH;
  int nn = min(512, n - base);
  h[t] = 0; h[t + 256] = 0;
  __syncthreads();
  int lo = bbase[b], hi = bbase[b + 1];
  for (int j = lo + t; j < hi; j += 256) atomicAdd(&h[(int)binned[j].y - base], 1);
  __syncthreads();
  if (t < nn) cnt[base + t] = h[t];
  if (t + 256 < nn) cnt[base + t + 256] = h[t + 256];
}

// ---------------- exclusive scan of cnt -> row_ptr (3 kernels) ---------------
__global__ __launch_bounds__(256) void k_scan1(const int* __restrict__ cnt,
                                               int* __restrict__ excl,
                                               int* __restrict__ blk_sums, int n) {
  __shared__ int sh[256];
  int t = threadIdx.x;
  int base = blockIdx.x * 1024 + t * 4;
  int4 v = {0, 0, 0, 0};
  if (base < n) v = *(const int4*)&cnt[base];
  int s = v.x + v.y + v.z + v.w;
  sh[t] = s;
  __syncthreads();
  for (int off = 1; off < 256; off <<= 1) {
    int x = (t >= off) ? sh[t - off] : 0;
    __syncthreads();
    sh[t] += x;
    __syncthreads();
  }
  int ex = sh[t] - s;
  if (t == 255) blk_sums[blockIdx.x] = sh[255];
  if (base < n) {
    excl[base]     = ex;
    excl[base + 1] = ex + v.x;
    excl[base + 2] = ex + v.x + v.y;
    excl[base + 3] = ex + v.x + v.y + v.z;
  }
}

__global__ void k_scan2(int* __restrict__ bs, int nb) {
  __shared__ int sh[128];
  int t = threadIdx.x;
  int v = (t < nb) ? bs[t] : 0;
  sh[t] = v;
  __syncthreads();
  for (int off = 1; off < 128; off <<= 1) {
    int x = (t >= off) ? sh[t - off] : 0;
    __syncthreads();
    sh[t] += x;
    __syncthreads();
  }
  if (t < nb) bs[t] = sh[t] - v;
}

__global__ __launch_bounds__(256) void k_scan3(int* __restrict__ rp, const int* __restrict__ bs,
                                               const int* __restrict__ cnt, int* __restrict__ cursor,
                                               float* __restrict__ deg, int n, int ne) {
  int i = blockIdx.x * 256 + threadIdx.x;
  if (i < n) {
    int r = rp[i] + bs[i >> 10];
    rp[i] = r;
    cursor[i] = r;
    int c = cnt[i];
    deg[i] = (float)(c > 0 ? c : 1);
  }
  if (i == 0) rp[n] = ne;
}

// ---------------- place edges into CSR (per-bucket LDS sort, coalesced) ------
__global__ __launch_bounds__(256) void k_place(const uint2* __restrict__ binned,
                                               const int* __restrict__ bbase,
                                               const int* __restrict__ rp,
                                               int* __restrict__ cursor,
                                               int* __restrict__ csr_src, int n) {
  int b = blockIdx.x, t = threadIdx.x;
  int base = b << BSH;
  int lo = bbase[b], hi = bbase[b + 1], m = hi - lo;
  if (m <= 0) return;
  if (m > PCAP) {                          // fallback: global-atomic scatter
    for (int j = lo + t; j < hi; j += 256) {
      uint2 e = binned[j];
      int p = atomicAdd(&cursor[(int)e.y], 1);
      csr_src[p] = (int)e.x;
    }
    return;
  }
  __shared__ int h[512], loff[512], wc[512], ss[256];
  __shared__ int stage[PCAP];
  h[t] = 0; h[t + 256] = 0;
  __syncthreads();
  for (int j = lo + t; j < hi; j += 256) atomicAdd(&h[(int)binned[j].y - base], 1);
  __syncthreads();
  int a0 = h[2 * t], a1 = h[2 * t + 1];
  int s = a0 + a1;
  ss[t] = s;
  __syncthreads();
  for (int o = 1; o < 256; o <<= 1) {
    int x = (t >= o) ? ss[t - o] : 0;
    __syncthreads();
    ss[t] += x;
    __syncthreads();
  }
  int ex = ss[t] - s;
  loff[2 * t] = ex; loff[2 * t + 1] = ex + a0;
  wc[2 * t] = ex;   wc[2 * t + 1] = ex + a0;
  __syncthreads();
  for (int j = lo + t; j < hi; j += 256) {
    uint2 e = binned[j];
    int p = atomicAdd(&wc[(int)e.y - base], 1);
    stage[p] = (int)e.x;
  }
  __syncthreads();
  int cb = rp[base];
  for (int j = t; j < m; j += 256) csr_src[cb + j] = stage[j];
}

// ----- init: identity BN, layer-0 beffS=b0, cN0=0, copy W0 -> Ws2/Wn2 --------
__global__ __launch_bounds__(256) void k_prep(const float* __restrict__ b0,
                                              float* __restrict__ ss0,
                                              float* __restrict__ beffS0,
                                              float* __restrict__ cN0,
                                              const uint4* __restrict__ Wst0,
                                              const uint4* __restrict__ Wnt0,
                                              uint4* __restrict__ Ws2,
                                              uint4* __restrict__ Wn2) {
  int id = blockIdx.x * 256 + threadIdx.x;     // 0..4095
  if (id < 128) {
    ss0[id] = 1.f; ss0[128 + id] = 0.f;
    beffS0[id] = b0[id]; cN0[id] = 0.f;
  }
  int half = id >> 11, ch = id & 2047;         // 2048 uint4 chunks each
  if (half) Wn2[ch] = Wnt0[ch]; else Ws2[ch] = Wst0[ch];
}

// ------- k_gemm2: Ys = hb@Ws2, Yn = hb@Wn2 (one staged A-tile) ---------------
__global__ __launch_bounds__(256) void k_gemm2(
    const __hip_bfloat16* __restrict__ hb,
    const __hip_bfloat16* __restrict__ Wst2, const __hip_bfloat16* __restrict__ Wnt2,
    __hip_bfloat16* __restrict__ Ys, __hip_bfloat16* __restrict__ Yn, int n) {
  __shared__ short Ah[128 * 128];
  int t = threadIdx.x;
  int row0 = blockIdx.x * 128;
  int w = t >> 6, lane = t & 63;

  // ---- async stage: 8 rounds, 16B/lane, LDS dest linear ----
#pragma unroll
  for (int rd = 0; rd < 8; ++rd) {
    int Gq = rd * 256 + w * 64 + lane;       // granule id 0..2047 (16B each)
    int r = Gq >> 4;                          // local row 0..127
    int gq = (Gq & 15) ^ (r & 7);             // pre-swizzled source granule
    int grow = row0 + r;
    grow = grow < n ? grow : n - 1;           // clamp: garbage rows never used
    const __hip_bfloat16* gs = hb + (size_t)grow * 128 + gq * 8;
    __builtin_amdgcn_global_load_lds((gconst_t*)gs,
        (ldsv_t*)&Ah[(rd * 256 + w * 64) * 8], 16, 0, 0);
  }
  asm volatile("s_waitcnt vmcnt(0)" ::: "memory");
  __syncthreads();

  int lr16 = lane & 15, hi = lane >> 4;
  const __hip_bfloat16* Bt[2] = {Wst2, Wnt2};
  __hip_bfloat16* Ot[2] = {Ys, Yn};
#pragma unroll
  for (int s = 0; s < 2; ++s) {
    const __hip_bfloat16* B = Bt[s];
    f32x4 acc[2][8];
#pragma unroll
    for (int fm = 0; fm < 2; ++fm)
#pragma unroll
      for (int fn = 0; fn < 8; ++fn) acc[fm][fn] = (f32x4){0.f, 0.f, 0.f, 0.f};
#pragma unroll
    for (int ks = 0; ks < 4; ++ks) {
      bf16x8 af[2], bfr[8];
#pragma unroll
      for (int fm = 0; fm < 2; ++fm) {
        int rl = w * 32 + fm * 16 + lr16;
        int gq = (ks * 4 + hi) ^ (lr16 & 7);
        af[fm] = *(const bf16x8*)&Ah[rl * 128 + gq * 8];
      }
#pragma unroll
      for (int fn = 0; fn < 8; ++fn)
        bfr[fn] = *(const bf16x8*)(B + (size_t)(fn * 16 + lr16) * 128 + ks * 32 + hi * 8);
#pragma unroll
      for (int fm = 0; fm < 2; ++fm)
#pragma unroll
        for (int fn = 0; fn < 8; ++fn)
          acc[fm][fn] = __builtin_amdgcn_mfma_f32_16x16x32_bf16(af[fm], bfr[fn], acc[fm][fn], 0, 0, 0);
    }
    // store this output (C/D: col = lane&15, row = 4*(lane>>4)+reg  [m89])
    __hip_bfloat16* O = Ot[s];
#pragma unroll
    for (int fm = 0; fm < 2; ++fm) {
      int rbase = row0 + w * 32 + fm * 16 + hi * 4;
#pragma unroll
      for (int fn = 0; fn < 8; ++fn) {
        int col = fn * 16 + lr16;
#pragma unroll
        for (int r = 0; r < 4; ++r) {
          int grow = rbase + r;
          if (grow < n) O[(size_t)grow * 128 + col] = __float2bfloat16(acc[fm][fn][r]);
        }
      }
    }
  }
}

// ------- k_agg: pure mean-gather of Yn rows -> aggY (bf16) -------------------
__device__ __forceinline__ void acc8(float* a, uint4 v) {
  float2 f;
  f = __bfloat1622float2(*(const __hip_bfloat162*)&v.x); a[0] += f.x; a[1] += f.y;
  f = __bfloat1622float2(*(const __hip_bfloat162*)&v.y); a[2] += f.x; a[3] += f.y;
  f = __bfloat1622float2(*(const __hip_bfloat162*)&v.z); a[4] += f.x; a[5] += f.y;
  f = __bfloat1622float2(*(const __hip_bfloat162*)&v.w); a[6] += f.x; a[7] += f.y;
}

__global__ __launch_bounds__(256) void k_agg(const uint4* __restrict__ yn4,
                                             const int* __restrict__ rp,
                                             const int* __restrict__ csr_src,
                                             const float* __restrict__ deg,
                                             uint4* __restrict__ aggY4, int n) {
  int lane = threadIdx.x & 63, wid = threadIdx.x >> 6;
  int g = lane >> 4, lr = lane & 15;
  for (int i = blockIdx.x * 4 + wid; i < n; i += gridDim.x * 4) {
    int beg = rp[i], end = rp[i + 1];
    float a[8];
#pragma unroll
    for (int c = 0; c < 8; ++c) a[c] = 0.f;
    int e = beg;
    for (; e + 8 <= end; e += 8) {        // 8 edges per wave-iteration
      int s0 = csr_src[e + g];
      int s1 = csr_src[e + 4 + g];
      uint4 v0 = yn4[(size_t)s0 * 16 + lr];
      uint4 v1 = yn4[(size_t)s1 * 16 + lr];
      acc8(a, v0);
      acc8(a, v1);
    }
    for (; e + g < end; e += 4) {         // predicated 4-edge tail
      int s = csr_src[e + g];
      uint4 v = yn4[(size_t)s * 16 + lr];
      acc8(a, v);
    }
#pragma unroll
    for (int c = 0; c < 8; ++c) {         // combine the 4 groups
      a[c] += __shfl_xor(a[c], 16, 64);
      a[c] += __shfl_xor(a[c], 32, 64);
    }
    if (g == 0) {
      float invd = 1.0f / deg[i];
      __hip_bfloat162 p0 = __float22bfloat162_rn(make_float2(a[0] * invd, a[1] * invd));
      __hip_bfloat162 p1 = __float22bfloat162_rn(make_float2(a[2] * invd, a[3] * invd));
      __hip_bfloat162 p2 = __float22bfloat162_rn(make_float2(a[4] * invd, a[5] * invd));
      __hip_bfloat162 p3 = __float22bfloat162_rn(make_float2(a[6] * invd, a[7] * invd));
      uint4 o;
      o.x = *(unsigned int*)&p0; o.y = *(unsigned int*)&p1;
      o.z = *(unsigned int*)&p2; o.w = *(unsigned int*)&p3;
      aggY4[(size_t)i * 16 + lr] = o;
    }
  }
}

// ------- k_finpool: rst = PReLU(Ys + beffS + [cnt>0: aggY + cN]);  -----------
// writes next hb; ONE block reduction feeds per-graph pool AND BN stats
// (rows are gid-sorted; each block's chunk lies in exactly one graph).
__global__ __launch_bounds__(256) void k_finpool(
    const uint4* __restrict__ ys4, const uint4* __restrict__ aggY4,
    const int* __restrict__ cnt,
    const float* __restrict__ beffS, const float* __restrict__ cN,
    const float* __restrict__ pw,
    const int* __restrict__ gstart, const int* __restrict__ gcnt,
    uint4* __restrict__ hbn4, float* __restrict__ out,
    float* __restrict__ partial, int l, int n) {
  __shared__ float redS[4][128], redQ[4][128];
  int g = blockIdx.x >> 3, c = blockIdx.x & 7;
  int len = gcnt[g];
  int i0 = gstart[g] + ((len * c) >> 3);
  int i1 = gstart[g] + ((len * (c + 1)) >> 3);
  if (i0 >= i1) return;                       // block-uniform
  int t = threadIdx.x, w = t >> 6, lane = t & 63;
  int gi = lane >> 4, lr = lane & 15;
  float bS[8], cn8[8], pw8[8], S[8], Q[8];
#pragma unroll
  for (int k = 0; k < 8; ++k) {
    bS[k] = beffS[lr * 8 + k];
    cn8[k] = cN[lr * 8 + k];
    pw8[k] = pw[lr * 8 + k];
    S[k] = 0.f; Q[k] = 0.f;
  }
  for (int r = i0 + w * 4 + gi; r < i1; r += 16) {   // 16 rows in flight
    uint4 ys = ys4[(size_t)r * 16 + lr];
    uint4 ag = aggY4[(size_t)r * 16 + lr];
    bool has = cnt[r] > 0;
    float y[8], a[8];
    float2 f;
    f = __bfloat1622float2(*(const __hip_bfloat162*)&ys.x); y[0] = f.x; y[1] = f.y;
    f = __bfloat1622float2(*(const __hip_bfloat162*)&ys.y); y[2] = f.x; y[3] = f.y;
    f = __bfloat1622float2(*(const __hip_bfloat162*)&ys.z); y[4] = f.x; y[5] = f.y;
    f = __bfloat1622float2(*(const __hip_bfloat162*)&ys.w); y[6] = f.x; y[7] = f.y;
    f = __bfloat1622float2(*(const __hip_bfloat162*)&ag.x); a[0] = f.x; a[1] = f.y;
    f = __bfloat1622float2(*(const __hip_bfloat162*)&ag.y); a[2] = f.x; a[3] = f.y;
    f = __bfloat1622float2(*(const __hip_bfloat162*)&ag.z); a[4] = f.x; a[5] = f.y;
    f = __bfloat1622float2(*(const __hip_bfloat162*)&ag.w); a[6] = f.x; a[7] = f.y;
    float x[8];
#pragma unroll
    for (int k = 0; k < 8; ++k) {
      float xx = y[k] + bS[k];
      if (has) xx += a[k] + cn8[k];
      xx = xx > 0.f ? xx : pw8[k] * xx;
      S[k] += xx; Q[k] += xx * xx;
      x[k] = xx;
    }
    __hip_bfloat162 p0 = __float22bfloat162_rn(make_float2(x[0], x[1]));
    __hip_bfloat162 p1 = __float22bfloat162_rn(make_float2(x[2], x[3]));
    __hip_bfloat162 p2 = __float22bfloat162_rn(make_float2(x[4], x[5]));
    __hip_bfloat162 p3 = __float22bfloat162_rn(make_float2(x[6], x[7]));
    uint4 o;
    o.x = *(unsigned int*)&p0; o.y = *(unsigned int*)&p1;
    o.z = *(unsigned int*)&p2; o.w = *(unsigned int*)&p3;
    hbn4[(size_t)r * 16 + lr] = o;
  }
#pragma unroll
  for (int k = 0; k < 8; ++k) {                      // combine 4 groups in wave
    S[k] += __shfl_xor(S[k], 16, 64);
    S[k] += __shfl_xor(S[k], 32, 64);
    Q[k] += __shfl_xor(Q[k], 16, 64);
    Q[k] += __shfl_xor(Q[k], 32, 64);
  }
  if (gi == 0) {
#pragma unroll
    for (int k = 0; k < 8; ++k) {
      redS[w][lr * 8 + k] = S[k];
      redQ[w][lr * 8 + k] = Q[k];
    }
  }
  __syncthreads();
  if (t < 128) {
    float s = redS[0][t] + redS[1][t] + redS[2][t] + redS[3][t];
    float q = redQ[0][t] + redQ[1][t] + redQ[2][t] + redQ[3][t];
    atomicAdd(&out[(size_t)g * 512 + l * 128 + t], s);
    float* pp = partial + (size_t)(blockIdx.x >> 5) * 256;
    atomicAdd(&pp[t], s);
    atomicAdd(&pp[128 + t], q);
  }
}

// ---- bnfin: stats -> BN affine; next-layer beffS/cN; W prescale; zero partial
__global__ __launch_bounds__(1024) void k_bnfin(float* __restrict__ partial, int nb,
                                                const float* __restrict__ gamma,
                                                const float* __restrict__ beta,
                                                float* __restrict__ ss,
                                                const float* __restrict__ bias_next,
                                                const float* __restrict__ Wsf_next,
                                                const float* __restrict__ Wnf_next,
                                                const __hip_bfloat16* __restrict__ Wst_next,
                                                const __hip_bfloat16* __restrict__ Wnt_next,
                                                __hip_bfloat16* __restrict__ Ws2,
                                                __hip_bfloat16* __restrict__ Wn2,
                                                float* __restrict__ beffS_next,
                                                float* __restrict__ cN_next,
                                                int has_next, int n) {
  __shared__ float red[4][256];
  __shared__ float shv[128], scv[128];
  __shared__ float bredS[8][128], bredN[8][128];
  int t = threadIdx.x, c = t & 255, part = t >> 8;
  float s = 0.f;
  for (int b = part; b < nb; b += 4) s += partial[(size_t)b * 256 + c];
  red[part][c] = s;
  __syncthreads();
  if (part == 0) red[0][c] = red[0][c] + red[1][c] + red[2][c] + red[3][c];
  __syncthreads();
  if (t < 128) {
    float inv_n = 1.0f / (float)n;
    float mu = red[0][t] * inv_n;
    float var = red[0][128 + t] * inv_n - mu * mu;
    float sc = rsqrtf(var + EPS_BN) * gamma[t];
    float sh = beta[t] - mu * sc;
    ss[t] = sc;
    ss[128 + t] = sh;
    shv[t] = sh;
    scv[t] = sc;
  }
  __syncthreads();
  if (has_next) {
    int cc = t & 127, kg = t >> 7;       // 8 k-groups x 128 channels
    float aS = 0.f, aN = 0.f;
#pragma unroll
    for (int k = kg * 16; k < kg * 16 + 16; ++k) {
      float sh = shv[k];
      aS += sh * Wsf_next[k * 128 + cc];
      aN += sh * Wnf_next[k * 128 + cc];
    }
    bredS[kg][cc] = aS;
    bredN[kg][cc] = aN;
    __syncthreads();
    if (t < 128) {
      float rS = bias_next[t], rN = 0.f;
#pragma unroll
      for (int kg2 = 0; kg2 < 8; ++kg2) { rS += bredS[kg2][t]; rN += bredN[kg2][t]; }
      beffS_next[t] = rS;
      cN_next[t] = rN;
    }
    // prescale next-layer Wt by sc[k]  (Wt layout [n][k], k = i & 127)
    for (int i = t; i < 16384; i += 1024) {
      float scf = scv[i & 127];
      Ws2[i] = __float2bfloat16(__bfloat162float(Wst_next[i]) * scf);
      Wn2[i] = __float2bfloat16(__bfloat162float(Wnt_next[i]) * scf);
    }
  }
  // zero partial for next layer's finpool
  for (int i = t; i < nb * 256; i += 1024) partial[i] = 0.f;
}

// ------------- finalize: mean + BN affine per layer section ------------------
__global__ __launch_bounds__(256) void k_div(float* __restrict__ out, const int* __restrict__ gcnt,
                                             const float* __restrict__ ssbuf, int m) {
  int i = blockIdx.x * 256 + threadIdx.x;
  if (i < m) {
    int g = i >> 9;
    int lc = i & 511;
    int l = lc >> 7, c = lc & 127;
    const float* ss = ssbuf + (l + 1) * 256;
    int cn = gcnt[g];
    out[i] = (cn > 0) ? (out[i] / (float)cn) * ss[c] + ss[128 + c] : 0.f;
  }
}

extern "C" void kernel_launch(void* const* d_in, const int* in_sizes, int n_in,
                              void* d_out, int out_size, void* d_ws, size_t ws_size,
                              hipStream_t stream) {
  const int*   in_feat = (const int*)d_in[0];
  const int*   src     = (const int*)d_in[1];
  const int*   dst     = (const int*)d_in[2];
  const int*   gid     = (const int*)d_in[3];
  const float* emb     = (const float*)d_in[4];
  const float* Wself   = (const float*)d_in[5];
  const float* Wneigh  = (const float*)d_in[6];
  const float* bvec    = (const float*)d_in[7];
  const float* gamma   = (const float*)d_in[8];
  const float* beta    = (const float*)d_in[9];
  const float* prelu   = (const float*)d_in[10];
  const int N = in_sizes[0];
  const int E = in_sizes[1];
  const int G = out_size / 512;
  float* out = (float*)d_out;
  const int NB = (N + 127) / 128;          // gemm blocks
  const int NP = (G * 8 + 31) / 32;        // stat slots (32 finpool blocks/slot)
  const int NBKT = (N + 511) >> BSH;       // buckets (<=256 for N<=128K)

  char* p = (char*)d_ws;
  size_t off = 0;
  auto take = [&](size_t bytes) { void* r = p + off; off += (bytes + 255) & ~(size_t)255; return r; };
  __hip_bfloat16* hb0   = (__hip_bfloat16*)take((size_t)N * 128 * 2);
  __hip_bfloat16* hb1   = (__hip_bfloat16*)take((size_t)N * 128 * 2);
  __hip_bfloat16* Ysb   = (__hip_bfloat16*)take((size_t)N * 128 * 2);
  __hip_bfloat16* Ynb   = (__hip_bfloat16*)take((size_t)N * 128 * 2);
  __hip_bfloat16* Wst   = (__hip_bfloat16*)take((size_t)4 * 128 * 128 * 2);
  __hip_bfloat16* Wnt   = (__hip_bfloat16*)take((size_t)4 * 128 * 128 * 2);
  __hip_bfloat16* Wst2  = (__hip_bfloat16*)take((size_t)128 * 128 * 2);
  __hip_bfloat16* Wnt2  = (__hip_bfloat16*)take((size_t)128 * 128 * 2);
  float* partial        = (float*)take((size_t)NP * 256 * 4);
  float* ssbuf          = (float*)take((size_t)5 * 256 * 4);  // [l][sc|sh], l=0 identity
  float* beffS          = (float*)take((size_t)4 * 128 * 4);
  float* cNb            = (float*)take((size_t)4 * 128 * 4);
  uint2* binned  = (uint2*)take((size_t)E * 8);
  int*   csr_src = (int*)take((size_t)E * 4);
  int*   cnt     = (int*)take((size_t)N * 4);
  int*   rp      = (int*)take((size_t)(N + 1) * 4);
  int*   cursor  = (int*)take((size_t)N * 4);
  float* deg     = (float*)take((size_t)N * 4);
  int*   bs      = (int*)take(512);
  int*   gcnt    = (int*)take((size_t)G * 4);
  int*   gstart  = (int*)take((size_t)G * 4);
  int*   bktcnt  = (int*)take((size_t)NBKT * 4);
  int*   bbase   = (int*)take((size_t)(NBKT + 1) * 4);
  int*   bcur    = (int*)take((size_t)NBKT * 4);
  if (off > ws_size) return;

  hipMemsetAsync(bktcnt, 0, (size_t)NBKT * 4, stream);
  hipMemsetAsync(partial, 0, (size_t)NP * 256 * 4, stream);
  hipMemsetAsync(d_out, 0, (size_t)out_size * 4, stream);

  k_embed<<<(N * 64 + 255) / 256, 256, 0, stream>>>(in_feat, emb, (__hip_bfloat162*)hb0, N);
  k_wconv<<<(4 * 128 * 128 + 255) / 256, 256, 0, stream>>>(Wself, Wst, 4 * 128 * 128);
  k_wconv<<<(4 * 128 * 128 + 255) / 256, 256, 0, stream>>>(Wneigh, Wnt, 4 * 128 * 128);
  k_gcount<<<1, 128, 0, stream>>>(gid, gcnt, gstart, N, G);

  int nbb = (E + BCHUNK - 1) / BCHUNK;
  k_bhist<<<nbb, 256, 0, stream>>>(dst, bktcnt, E, NBKT);
  k_bscan<<<1, 256, 0, stream>>>(bktcnt, bbase, bcur, E, NBKT);
  k_bin<<<nbb, 256, 0, stream>>>(src, dst, bcur, binned, E, NBKT);
  k_cnt<<<NBKT, 256, 0, stream>>>(binned, bbase, cnt, N);
  int nsb = (N + 1023) / 1024;
  k_scan1<<<nsb, 256, 0, stream>>>(cnt, rp, bs, N);
  k_scan2<<<1, 128, 0, stream>>>(bs, nsb);
  k_scan3<<<(N + 255) / 256, 256, 0, stream>>>(rp, bs, cnt, cursor, deg, N, E);
  k_place<<<NBKT, 256, 0, stream>>>(binned, bbase, rp, cursor, csr_src, N);
  k_prep<<<16, 256, 0, stream>>>(bvec, ssbuf, beffS, cNb,
                                 (const uint4*)Wst, (const uint4*)Wnt,
                                 (uint4*)Wst2, (uint4*)Wnt2);

  __hip_bfloat16* bufs[2] = {hb0, hb1};
  for (int l = 0; l < 4; ++l) {
    __hip_bfloat16* hin  = bufs[l & 1];
    __hip_bfloat16* hout = bufs[(l + 1) & 1];
    k_gemm2<<<NB, 256, 0, stream>>>(hin, Wst2, Wnt2, Ysb, Ynb, N);
    // hin is dead after gemm2 staged it -> reuse as aggY
    k_agg<<<AGG_BLOCKS, 256, 0, stream>>>((const uint4*)Ynb, rp, csr_src, deg,
                                          (uint4*)hin, N);
    k_finpool<<<G * 8, 256, 0, stream>>>((const uint4*)Ysb, (const uint4*)hin, cnt,
                                         beffS + l * 128, cNb + l * 128,
                                         prelu + l * 128, gstart, gcnt,
                                         (uint4*)hout, out, partial, l, N);
    k_bnfin<<<1, 1024, 0, stream>>>(partial, NP, gamma + l * 128, beta + l * 128,
                                    ssbuf + (l + 1) * 256,
                                    bvec + ((l + 1) & 3) * 128,
                                    Wself + ((l + 1) & 3) * 16384,
                                    Wneigh + ((l + 1) & 3) * 16384,
                                    Wst + ((l + 1) & 3) * 16384,
                                    Wnt + ((l + 1) & 3) * 16384,
                                    Wst2, Wnt2,
                                    beffS + ((l + 1) & 3) * 128,
                                    cNb + ((l + 1) & 3) * 128,
                                    (l < 3) ? 1 : 0, N);
  }
  k_div<<<(out_size + 255) / 256, 256, 0, stream>>>(out, gcnt, ssbuf, out_size);
}

// Round 14
// 584.857 us; speedup vs baseline: 1.1936x; 1.0201x over previous
//
#include <hip/hip_runtime.h>
#include <hip/hip_bf16.h>

// GraphSAGE 4-layer forward.
// R2-R5: bf16 activations; MFMA GEMM; BN folded forward; binned CSR build.
// R6-R13: GEMM staging wall ~711 GB/s regardless of schedule -> time = bytes/wall.
// R14: Y-space restructure (agg commutes with W): gemm2 stages ONE tile.
// R15: pure gather k_agg + finish fused into pool (k_finpool) -> 596us.
// R16: k_agg pipeline deepened -- 16-edge main loop (4 row-loads in flight
//     per lane, VGPR 20->~36) for deg>=16 nodes; k_wconv merged to one
//     dispatch; k_embed vectorized to 16B/thread.

#define EPS_BN 1e-5f
#define BSH 9                 // 512 nodes per bucket
#define BCHUNK 4096           // edges per k_bin block
#define PCAP 10240            // max edges per bucket for LDS staging (mean 8192)
#define AGG_BLOCKS 2048

typedef __attribute__((ext_vector_type(8))) short bf16x8;
typedef __attribute__((ext_vector_type(4))) float f32x4;
typedef __attribute__((address_space(1))) const void gconst_t;
typedef __attribute__((address_space(3))) void ldsv_t;

// ---------------- embedding gather -> bf16 h (16B/thread) --------------------
__global__ __launch_bounds__(256) void k_embed(const int* __restrict__ feat,
                                               const float* __restrict__ emb,
                                               uint4* __restrict__ hb4, int n) {
  int idx = blockIdx.x * 256 + threadIdx.x;   // one uint4 (8 channels) each
  if (idx < n * 16) {
    int i = idx >> 4, c8 = idx & 15;
    const float4* e = (const float4*)(emb + (size_t)feat[i] * 128 + c8 * 8);
    float4 f0 = e[0], f1 = e[1];
    __hip_bfloat162 p0 = __float22bfloat162_rn(make_float2(f0.x, f0.y));
    __hip_bfloat162 p1 = __float22bfloat162_rn(make_float2(f0.z, f0.w));
    __hip_bfloat162 p2 = __float22bfloat162_rn(make_float2(f1.x, f1.y));
    __hip_bfloat162 p3 = __float22bfloat162_rn(make_float2(f1.z, f1.w));
    uint4 o;
    o.x = *(unsigned int*)&p0; o.y = *(unsigned int*)&p1;
    o.z = *(unsigned int*)&p2; o.w = *(unsigned int*)&p3;
    hb4[idx] = o;
  }
}

// ------ W -> bf16, transposed, BOTH matrices in one dispatch -----------------
__global__ __launch_bounds__(256) void k_wconv(const float* __restrict__ Ws,
                                               const float* __restrict__ Wn,
                                               __hip_bfloat16* __restrict__ Wst,
                                               __hip_bfloat16* __restrict__ Wnt) {
  int idx = blockIdx.x * 256 + threadIdx.x;   // 0 .. 2*65536-1
  int half = idx >> 16, r = idx & 65535;
  int l = r >> 14, rr = r & 16383, nn = rr >> 7, kk = rr & 127;
  const float* W = half ? Wn : Ws;
  __hip_bfloat16* Wt = half ? Wnt : Wst;
  Wt[r] = __float2bfloat16(W[(l << 14) + kk * 128 + nn]);
}

// ---------------- per-graph node offsets via binary search (gid sorted) ------
__global__ void k_gcount(const int* __restrict__ gid, int* __restrict__ gcnt,
                         int* __restrict__ gstart, int n, int G) {
  int g = blockIdx.x * blockDim.x + threadIdx.x;
  if (g >= G) return;
  int lo0 = 0, hi = n;
  while (lo0 < hi) { int mid = (lo0 + hi) >> 1; if (gid[mid] < g) lo0 = mid + 1; else hi = mid; }
  int lo1 = lo0; hi = n;
  while (lo1 < hi) { int mid = (lo1 + hi) >> 1; if (gid[mid] < g + 1) lo1 = mid + 1; else hi = mid; }
  gstart[g] = lo0;
  gcnt[g] = lo1 - lo0;
}

// ---------------- bucket histogram over dst (LDS-staged) ---------------------
__global__ __launch_bounds__(256) void k_bhist(const int* __restrict__ dst,
                                               int* __restrict__ bktcnt, int m, int nbkt) {
  __shared__ int h[256];
  int t = threadIdx.x;
  h[t] = 0;
  __syncthreads();
#pragma unroll
  for (int k = 0; k < 4; ++k) {
    int idx = blockIdx.x * BCHUNK + k * 1024 + t * 4;
    if (idx + 4 <= m) {
      int4 d = *(const int4*)&dst[idx];
      atomicAdd(&h[d.x >> BSH], 1);
      atomicAdd(&h[d.y >> BSH], 1);
      atomicAdd(&h[d.z >> BSH], 1);
      atomicAdd(&h[d.w >> BSH], 1);
    } else {
      for (int e = idx; e < m && e < idx + 4; ++e) atomicAdd(&h[dst[e] >> BSH], 1);
    }
  }
  __syncthreads();
  for (int b = t; b < nbkt; b += 256)
    if (h[b]) atomicAdd(&bktcnt[b], h[b]);
}

// ---------------- scan bucket counts -> base & cursor ------------------------
__global__ void k_bscan(const int* __restrict__ bktcnt, int* __restrict__ bbase,
                        int* __restrict__ bcur, int m, int nbkt) {
  __shared__ int sh[256];
  int t = threadIdx.x;
  int v = (t < nbkt) ? bktcnt[t] : 0;
  sh[t] = v;
  __syncthreads();
  for (int o = 1; o < 256; o <<= 1) {
    int x = (t >= o) ? sh[t - o] : 0;
    __syncthreads();
    sh[t] += x;
    __syncthreads();
  }
  if (t < nbkt) { bbase[t] = sh[t] - v; bcur[t] = sh[t] - v; }
  if (t == 0) bbase[nbkt] = m;
}

// ---------------- bin edges by bucket (LDS counting sort, coalesced out) -----
__global__ __launch_bounds__(256) void k_bin(const int* __restrict__ src, const int* __restrict__ dst,
                                             int* __restrict__ bcur, uint2* __restrict__ binned,
                                             int m, int nbkt) {
  __shared__ uint2 st[BCHUNK];
  __shared__ int bcnt[256], boff[256], bres[256], wcur[256], ss[256];
  int t = threadIdx.x;
  int e0 = blockIdx.x * BCHUNK;
  int cn = min(BCHUNK, m - e0);
  int sv[16], dv[16];
  for (int b = t; b < 256; b += 256) bcnt[b] = 0;
  __syncthreads();
#pragma unroll
  for (int k = 0; k < 16; ++k) {
    int idx = e0 + k * 256 + t;
    if (idx < e0 + cn) {
      sv[k] = src[idx];
      dv[k] = dst[idx];
      atomicAdd(&bcnt[dv[k] >> BSH], 1);
    } else dv[k] = -1;
  }
  __syncthreads();
  int v = (t < nbkt) ? bcnt[t] : 0;
  ss[t] = v;
  __syncthreads();
  for (int o = 1; o < 256; o <<= 1) {
    int x = (t >= o) ? ss[t - o] : 0;
    __syncthreads();
    ss[t] += x;
    __syncthreads();
  }
  if (t < nbkt) {
    int ex = ss[t] - v;
    boff[t] = ex;
    wcur[t] = ex;
    if (v) bres[t] = atomicAdd(&bcur[t], v);
  }
  __syncthreads();
#pragma unroll
  for (int k = 0; k < 16; ++k) {
    if (dv[k] >= 0) {
      int b = dv[k] >> BSH;
      int p = atomicAdd(&wcur[b], 1);
      st[p] = make_uint2((unsigned)sv[k], (unsigned)dv[k]);
    }
  }
  __syncthreads();
  for (int j = t; j < cn; j += 256) {
    uint2 e = st[j];
    int b = (int)(e.y >> BSH);
    binned[(size_t)bres[b] + (j - boff[b])] = e;
  }
}

// ---------------- per-bucket node counts (LDS, coalesced cnt write) ----------
__global__ __launch_bounds__(256) void k_cnt(const uint2* __restrict__ binned,
                                             const int* __restrict__ bbase,
                                             int* __restrict__ cnt, int n) {
  __shared__ int h[512];
  int b = blockIdx.x, t = threadIdx.x;
  int base = b << BSH;
  int nn = min(512, n - base);
  h[t] = 0; h[t + 256] = 0;
  __syncthreads();
  int lo = bbase[b], hi = bbase[b + 1];
  for (int j = lo + t; j < hi; j += 256) atomicAdd(&h[(int)binned[j].y - base], 1);
  __syncthreads();
  if (t < nn) cnt[base + t] = h[t];
  if (t + 256 < nn) cnt[base + t + 256] = h[t + 256];
}

// ---------------- exclusive scan of cnt -> row_ptr (3 kernels) ---------------
__global__ __launch_bounds__(256) void k_scan1(const int* __restrict__ cnt,
                                               int* __restrict__ excl,
                                               int* __restrict__ blk_sums, int n) {
  __shared__ int sh[256];
  int t = threadIdx.x;
  int base = blockIdx.x * 1024 + t * 4;
  int4 v = {0, 0, 0, 0};
  if (base < n) v = *(const int4*)&cnt[base];
  int s = v.x + v.y + v.z + v.w;
  sh[t] = s;
  __syncthreads();
  for (int off = 1; off < 256; off <<= 1) {
    int x = (t >= off) ? sh[t - off] : 0;
    __syncthreads();
    sh[t] += x;
    __syncthreads();
  }
  int ex = sh[t] - s;
  if (t == 255) blk_sums[blockIdx.x] = sh[255];
  if (base < n) {
    excl[base]     = ex;
    excl[base + 1] = ex + v.x;
    excl[base + 2] = ex + v.x + v.y;
    excl[base + 3] = ex + v.x + v.y + v.z;
  }
}

__global__ void k_scan2(int* __restrict__ bs, int nb) {
  __shared__ int sh[128];
  int t = threadIdx.x;
  int v = (t < nb) ? bs[t] : 0;
  sh[t] = v;
  __syncthreads();
  for (int off = 1; off < 128; off <<= 1) {
    int x = (t >= off) ? sh[t - off] : 0;
    __syncthreads();
    sh[t] += x;
    __syncthreads();
  }
  if (t < nb) bs[t] = sh[t] - v;
}

__global__ __launch_bounds__(256) void k_scan3(int* __restrict__ rp, const int* __restrict__ bs,
                                               const int* __restrict__ cnt, int* __restrict__ cursor,
                                               float* __restrict__ deg, int n, int ne) {
  int i = blockIdx.x * 256 + threadIdx.x;
  if (i < n) {
    int r = rp[i] + bs[i >> 10];
    rp[i] = r;
    cursor[i] = r;
    int c = cnt[i];
    deg[i] = (float)(c > 0 ? c : 1);
  }
  if (i == 0) rp[n] = ne;
}

// ---------------- place edges into CSR (per-bucket LDS sort, coalesced) ------
__global__ __launch_bounds__(256) void k_place(const uint2* __restrict__ binned,
                                               const int* __restrict__ bbase,
                                               const int* __restrict__ rp,
                                               int* __restrict__ cursor,
                                               int* __restrict__ csr_src, int n) {
  int b = blockIdx.x, t = threadIdx.x;
  int base = b << BSH;
  int lo = bbase[b], hi = bbase[b + 1], m = hi - lo;
  if (m <= 0) return;
  if (m > PCAP) {                          // fallback: global-atomic scatter
    for (int j = lo + t; j < hi; j += 256) {
      uint2 e = binned[j];
      int p = atomicAdd(&cursor[(int)e.y], 1);
      csr_src[p] = (int)e.x;
    }
    return;
  }
  __shared__ int h[512], loff[512], wc[512], ss[256];
  __shared__ int stage[PCAP];
  h[t] = 0; h[t + 256] = 0;
  __syncthreads();
  for (int j = lo + t; j < hi; j += 256) atomicAdd(&h[(int)binned[j].y - base], 1);
  __syncthreads();
  int a0 = h[2 * t], a1 = h[2 * t + 1];
  int s = a0 + a1;
  ss[t] = s;
  __syncthreads();
  for (int o = 1; o < 256; o <<= 1) {
    int x = (t >= o) ? ss[t - o] : 0;
    __syncthreads();
    ss[t] += x;
    __syncthreads();
  }
  int ex = ss[t] - s;
  loff[2 * t] = ex; loff[2 * t + 1] = ex + a0;
  wc[2 * t] = ex;   wc[2 * t + 1] = ex + a0;
  __syncthreads();
  for (int j = lo + t; j < hi; j += 256) {
    uint2 e = binned[j];
    int p = atomicAdd(&wc[(int)e.y - base], 1);
    stage[p] = (int)e.x;
  }
  __syncthreads();
  int cb = rp[base];
  for (int j = t; j < m; j += 256) csr_src[cb + j] = stage[j];
}

// ----- init: identity BN, layer-0 beffS=b0, cN0=0, copy W0 -> Ws2/Wn2 --------
__global__ __launch_bounds__(256) void k_prep(const float* __restrict__ b0,
                                              float* __restrict__ ss0,
                                              float* __restrict__ beffS0,
                                              float* __restrict__ cN0,
                                              const uint4* __restrict__ Wst0,
                                              const uint4* __restrict__ Wnt0,
                                              uint4* __restrict__ Ws2,
                                              uint4* __restrict__ Wn2) {
  int id = blockIdx.x * 256 + threadIdx.x;     // 0..4095
  if (id < 128) {
    ss0[id] = 1.f; ss0[128 + id] = 0.f;
    beffS0[id] = b0[id]; cN0[id] = 0.f;
  }
  int half = id >> 11, ch = id & 2047;         // 2048 uint4 chunks each
  if (half) Wn2[ch] = Wnt0[ch]; else Ws2[ch] = Wst0[ch];
}

// ------- k_gemm2: Ys = hb@Ws2, Yn = hb@Wn2 (one staged A-tile) ---------------
__global__ __launch_bounds__(256) void k_gemm2(
    const __hip_bfloat16* __restrict__ hb,
    const __hip_bfloat16* __restrict__ Wst2, const __hip_bfloat16* __restrict__ Wnt2,
    __hip_bfloat16* __restrict__ Ys, __hip_bfloat16* __restrict__ Yn, int n) {
  __shared__ short Ah[128 * 128];
  int t = threadIdx.x;
  int row0 = blockIdx.x * 128;
  int w = t >> 6, lane = t & 63;

  // ---- async stage: 8 rounds, 16B/lane, LDS dest linear ----
#pragma unroll
  for (int rd = 0; rd < 8; ++rd) {
    int Gq = rd * 256 + w * 64 + lane;       // granule id 0..2047 (16B each)
    int r = Gq >> 4;                          // local row 0..127
    int gq = (Gq & 15) ^ (r & 7);             // pre-swizzled source granule
    int grow = row0 + r;
    grow = grow < n ? grow : n - 1;           // clamp: garbage rows never used
    const __hip_bfloat16* gs = hb + (size_t)grow * 128 + gq * 8;
    __builtin_amdgcn_global_load_lds((gconst_t*)gs,
        (ldsv_t*)&Ah[(rd * 256 + w * 64) * 8], 16, 0, 0);
  }
  asm volatile("s_waitcnt vmcnt(0)" ::: "memory");
  __syncthreads();

  int lr16 = lane & 15, hi = lane >> 4;
  const __hip_bfloat16* Bt[2] = {Wst2, Wnt2};
  __hip_bfloat16* Ot[2] = {Ys, Yn};
#pragma unroll
  for (int s = 0; s < 2; ++s) {
    const __hip_bfloat16* B = Bt[s];
    f32x4 acc[2][8];
#pragma unroll
    for (int fm = 0; fm < 2; ++fm)
#pragma unroll
      for (int fn = 0; fn < 8; ++fn) acc[fm][fn] = (f32x4){0.f, 0.f, 0.f, 0.f};
#pragma unroll
    for (int ks = 0; ks < 4; ++ks) {
      bf16x8 af[2], bfr[8];
#pragma unroll
      for (int fm = 0; fm < 2; ++fm) {
        int rl = w * 32 + fm * 16 + lr16;
        int gq = (ks * 4 + hi) ^ (lr16 & 7);
        af[fm] = *(const bf16x8*)&Ah[rl * 128 + gq * 8];
      }
#pragma unroll
      for (int fn = 0; fn < 8; ++fn)
        bfr[fn] = *(const bf16x8*)(B + (size_t)(fn * 16 + lr16) * 128 + ks * 32 + hi * 8);
#pragma unroll
      for (int fm = 0; fm < 2; ++fm)
#pragma unroll
        for (int fn = 0; fn < 8; ++fn)
          acc[fm][fn] = __builtin_amdgcn_mfma_f32_16x16x32_bf16(af[fm], bfr[fn], acc[fm][fn], 0, 0, 0);
    }
    // store this output (C/D: col = lane&15, row = 4*(lane>>4)+reg  [m89])
    __hip_bfloat16* O = Ot[s];
#pragma unroll
    for (int fm = 0; fm < 2; ++fm) {
      int rbase = row0 + w * 32 + fm * 16 + hi * 4;
#pragma unroll
      for (int fn = 0; fn < 8; ++fn) {
        int col = fn * 16 + lr16;
#pragma unroll
        for (int r = 0; r < 4; ++r) {
          int grow = rbase + r;
          if (grow < n) O[(size_t)grow * 128 + col] = __float2bfloat16(acc[fm][fn][r]);
        }
      }
    }
  }
}

// ------- k_agg: pure mean-gather of Yn rows -> aggY (bf16) -------------------
// R16: deg-split pipeline -- 16-edge main loop keeps 4 row-loads in flight
// per lane; 8-edge and predicated 4-edge loops below it.
__device__ __forceinline__ void acc8(float* a, uint4 v) {
  float2 f;
  f = __bfloat1622float2(*(const __hip_bfloat162*)&v.x); a[0] += f.x; a[1] += f.y;
  f = __bfloat1622float2(*(const __hip_bfloat162*)&v.y); a[2] += f.x; a[3] += f.y;
  f = __bfloat1622float2(*(const __hip_bfloat162*)&v.z); a[4] += f.x; a[5] += f.y;
  f = __bfloat1622float2(*(const __hip_bfloat162*)&v.w); a[6] += f.x; a[7] += f.y;
}

__global__ __launch_bounds__(256) void k_agg(const uint4* __restrict__ yn4,
                                             const int* __restrict__ rp,
                                             const int* __restrict__ csr_src,
                                             const float* __restrict__ deg,
                                             uint4* __restrict__ aggY4, int n) {
  int lane = threadIdx.x & 63, wid = threadIdx.x >> 6;
  int g = lane >> 4, lr = lane & 15;
  for (int i = blockIdx.x * 4 + wid; i < n; i += gridDim.x * 4) {
    int beg = rp[i], end = rp[i + 1];
    float a[8];
#pragma unroll
    for (int c = 0; c < 8; ++c) a[c] = 0.f;
    int e = beg;
    for (; e + 16 <= end; e += 16) {      // 16 edges: 4 row-loads in flight
      int s0 = csr_src[e + g];
      int s1 = csr_src[e + 4 + g];
      int s2 = csr_src[e + 8 + g];
      int s3 = csr_src[e + 12 + g];
      uint4 v0 = yn4[(size_t)s0 * 16 + lr];
      uint4 v1 = yn4[(size_t)s1 * 16 + lr];
      uint4 v2 = yn4[(size_t)s2 * 16 + lr];
      uint4 v3 = yn4[(size_t)s3 * 16 + lr];
      acc8(a, v0);
      acc8(a, v1);
      acc8(a, v2);
      acc8(a, v3);
    }
    for (; e + 8 <= end; e += 8) {        // 8 edges: 2 in flight
      int s0 = csr_src[e + g];
      int s1 = csr_src[e + 4 + g];
      uint4 v0 = yn4[(size_t)s0 * 16 + lr];
      uint4 v1 = yn4[(size_t)s1 * 16 + lr];
      acc8(a, v0);
      acc8(a, v1);
    }
    for (; e + g < end; e += 4) {         // predicated 4-edge tail
      int s = csr_src[e + g];
      uint4 v = yn4[(size_t)s * 16 + lr];
      acc8(a, v);
    }
#pragma unroll
    for (int c = 0; c < 8; ++c) {         // combine the 4 groups
      a[c] += __shfl_xor(a[c], 16, 64);
      a[c] += __shfl_xor(a[c], 32, 64);
    }
    if (g == 0) {
      float invd = 1.0f / deg[i];
      __hip_bfloat162 p0 = __float22bfloat162_rn(make_float2(a[0] * invd, a[1] * invd));
      __hip_bfloat162 p1 = __float22bfloat162_rn(make_float2(a[2] * invd, a[3] * invd));
      __hip_bfloat162 p2 = __float22bfloat162_rn(make_float2(a[4] * invd, a[5] * invd));
      __hip_bfloat162 p3 = __float22bfloat162_rn(make_float2(a[6] * invd, a[7] * invd));
      uint4 o;
      o.x = *(unsigned int*)&p0; o.y = *(unsigned int*)&p1;
      o.z = *(unsigned int*)&p2; o.w = *(unsigned int*)&p3;
      aggY4[(size_t)i * 16 + lr] = o;
    }
  }
}

// ------- k_finpool: rst = PReLU(Ys + beffS + [cnt>0: aggY + cN]);  -----------
// writes next hb; ONE block reduction feeds per-graph pool AND BN stats
// (rows are gid-sorted; each block's chunk lies in exactly one graph).
__global__ __launch_bounds__(256) void k_finpool(
    const uint4* __restrict__ ys4, const uint4* __restrict__ aggY4,
    const int* __restrict__ cnt,
    const float* __restrict__ beffS, const float* __restrict__ cN,
    const float* __restrict__ pw,
    const int* __restrict__ gstart, const int* __restrict__ gcnt,
    uint4* __restrict__ hbn4, float* __restrict__ out,
    float* __restrict__ partial, int l, int n) {
  __shared__ float redS[4][128], redQ[4][128];
  int g = blockIdx.x >> 3, c = blockIdx.x & 7;
  int len = gcnt[g];
  int i0 = gstart[g] + ((len * c) >> 3);
  int i1 = gstart[g] + ((len * (c + 1)) >> 3);
  if (i0 >= i1) return;                       // block-uniform
  int t = threadIdx.x, w = t >> 6, lane = t & 63;
  int gi = lane >> 4, lr = lane & 15;
  float bS[8], cn8[8], pw8[8], S[8], Q[8];
#pragma unroll
  for (int k = 0; k < 8; ++k) {
    bS[k] = beffS[lr * 8 + k];
    cn8[k] = cN[lr * 8 + k];
    pw8[k] = pw[lr * 8 + k];
    S[k] = 0.f; Q[k] = 0.f;
  }
  for (int r = i0 + w * 4 + gi; r < i1; r += 16) {   // 16 rows in flight
    uint4 ys = ys4[(size_t)r * 16 + lr];
    uint4 ag = aggY4[(size_t)r * 16 + lr];
    bool has = cnt[r] > 0;
    float y[8], a[8];
    float2 f;
    f = __bfloat1622float2(*(const __hip_bfloat162*)&ys.x); y[0] = f.x; y[1] = f.y;
    f = __bfloat1622float2(*(const __hip_bfloat162*)&ys.y); y[2] = f.x; y[3] = f.y;
    f = __bfloat1622float2(*(const __hip_bfloat162*)&ys.z); y[4] = f.x; y[5] = f.y;
    f = __bfloat1622float2(*(const __hip_bfloat162*)&ys.w); y[6] = f.x; y[7] = f.y;
    f = __bfloat1622float2(*(const __hip_bfloat162*)&ag.x); a[0] = f.x; a[1] = f.y;
    f = __bfloat1622float2(*(const __hip_bfloat162*)&ag.y); a[2] = f.x; a[3] = f.y;
    f = __bfloat1622float2(*(const __hip_bfloat162*)&ag.z); a[4] = f.x; a[5] = f.y;
    f = __bfloat1622float2(*(const __hip_bfloat162*)&ag.w); a[6] = f.x; a[7] = f.y;
    float x[8];
#pragma unroll
    for (int k = 0; k < 8; ++k) {
      float xx = y[k] + bS[k];
      if (has) xx += a[k] + cn8[k];
      xx = xx > 0.f ? xx : pw8[k] * xx;
      S[k] += xx; Q[k] += xx * xx;
      x[k] = xx;
    }
    __hip_bfloat162 p0 = __float22bfloat162_rn(make_float2(x[0], x[1]));
    __hip_bfloat162 p1 = __float22bfloat162_rn(make_float2(x[2], x[3]));
    __hip_bfloat162 p2 = __float22bfloat162_rn(make_float2(x[4], x[5]));
    __hip_bfloat162 p3 = __float22bfloat162_rn(make_float2(x[6], x[7]));
    uint4 o;
    o.x = *(unsigned int*)&p0; o.y = *(unsigned int*)&p1;
    o.z = *(unsigned int*)&p2; o.w = *(unsigned int*)&p3;
    hbn4[(size_t)r * 16 + lr] = o;
  }
#pragma unroll
  for (int k = 0; k < 8; ++k) {                      // combine 4 groups in wave
    S[k] += __shfl_xor(S[k], 16, 64);
    S[k] += __shfl_xor(S[k], 32, 64);
    Q[k] += __shfl_xor(Q[k], 16, 64);
    Q[k] += __shfl_xor(Q[k], 32, 64);
  }
  if (gi == 0) {
#pragma unroll
    for (int k = 0; k < 8; ++k) {
      redS[w][lr * 8 + k] = S[k];
      redQ[w][lr * 8 + k] = Q[k];
    }
  }
  __syncthreads();
  if (t < 128) {
    float s = redS[0][t] + redS[1][t] + redS[2][t] + redS[3][t];
    float q = redQ[0][t] + redQ[1][t] + redQ[2][t] + redQ[3][t];
    atomicAdd(&out[(size_t)g * 512 + l * 128 + t], s);
    float* pp = partial + (size_t)(blockIdx.x >> 5) * 256;
    atomicAdd(&pp[t], s);
    atomicAdd(&pp[128 + t], q);
  }
}

// ---- bnfin: stats -> BN affine; next-layer beffS/cN; W prescale; zero partial
__global__ __launch_bounds__(1024) void k_bnfin(float* __restrict__ partial, int nb,
                                                const float* __restrict__ gamma,
                                                const float* __restrict__ beta,
                                                float* __restrict__ ss,
                                                const float* __restrict__ bias_next,
                                                const float* __restrict__ Wsf_next,
                                                const float* __restrict__ Wnf_next,
                                                const __hip_bfloat16* __restrict__ Wst_next,
                                                const __hip_bfloat16* __restrict__ Wnt_next,
                                                __hip_bfloat16* __restrict__ Ws2,
                                                __hip_bfloat16* __restrict__ Wn2,
                                                float* __restrict__ beffS_next,
                                                float* __restrict__ cN_next,
                                                int has_next, int n) {
  __shared__ float red[4][256];
  __shared__ float shv[128], scv[128];
  __shared__ float bredS[8][128], bredN[8][128];
  int t = threadIdx.x, c = t & 255, part = t >> 8;
  float s = 0.f;
  for (int b = part; b < nb; b += 4) s += partial[(size_t)b * 256 + c];
  red[part][c] = s;
  __syncthreads();
  if (part == 0) red[0][c] = red[0][c] + red[1][c] + red[2][c] + red[3][c];
  __syncthreads();
  if (t < 128) {
    float inv_n = 1.0f / (float)n;
    float mu = red[0][t] * inv_n;
    float var = red[0][128 + t] * inv_n - mu * mu;
    float sc = rsqrtf(var + EPS_BN) * gamma[t];
    float sh = beta[t] - mu * sc;
    ss[t] = sc;
    ss[128 + t] = sh;
    shv[t] = sh;
    scv[t] = sc;
  }
  __syncthreads();
  if (has_next) {
    int cc = t & 127, kg = t >> 7;       // 8 k-groups x 128 channels
    float aS = 0.f, aN = 0.f;
#pragma unroll
    for (int k = kg * 16; k < kg * 16 + 16; ++k) {
      float sh = shv[k];
      aS += sh * Wsf_next[k * 128 + cc];
      aN += sh * Wnf_next[k * 128 + cc];
    }
    bredS[kg][cc] = aS;
    bredN[kg][cc] = aN;
    __syncthreads();
    if (t < 128) {
      float rS = bias_next[t], rN = 0.f;
#pragma unroll
      for (int kg2 = 0; kg2 < 8; ++kg2) { rS += bredS[kg2][t]; rN += bredN[kg2][t]; }
      beffS_next[t] = rS;
      cN_next[t] = rN;
    }
    // prescale next-layer Wt by sc[k]  (Wt layout [n][k], k = i & 127)
    for (int i = t; i < 16384; i += 1024) {
      float scf = scv[i & 127];
      Ws2[i] = __float2bfloat16(__bfloat162float(Wst_next[i]) * scf);
      Wn2[i] = __float2bfloat16(__bfloat162float(Wnt_next[i]) * scf);
    }
  }
  // zero partial for next layer's finpool
  for (int i = t; i < nb * 256; i += 1024) partial[i] = 0.f;
}

// ------------- finalize: mean + BN affine per layer section ------------------
__global__ __launch_bounds__(256) void k_div(float* __restrict__ out, const int* __restrict__ gcnt,
                                             const float* __restrict__ ssbuf, int m) {
  int i = blockIdx.x * 256 + threadIdx.x;
  if (i < m) {
    int g = i >> 9;
    int lc = i & 511;
    int l = lc >> 7, c = lc & 127;
    const float* ss = ssbuf + (l + 1) * 256;
    int cn = gcnt[g];
    out[i] = (cn > 0) ? (out[i] / (float)cn) * ss[c] + ss[128 + c] : 0.f;
  }
}

extern "C" void kernel_launch(void* const* d_in, const int* in_sizes, int n_in,
                              void* d_out, int out_size, void* d_ws, size_t ws_size,
                              hipStream_t stream) {
  const int*   in_feat = (const int*)d_in[0];
  const int*   src     = (const int*)d_in[1];
  const int*   dst     = (const int*)d_in[2];
  const int*   gid     = (const int*)d_in[3];
  const float* emb     = (const float*)d_in[4];
  const float* Wself   = (const float*)d_in[5];
  const float* Wneigh  = (const float*)d_in[6];
  const float* bvec    = (const float*)d_in[7];
  const float* gamma   = (const float*)d_in[8];
  const float* beta    = (const float*)d_in[9];
  const float* prelu   = (const float*)d_in[10];
  const int N = in_sizes[0];
  const int E = in_sizes[1];
  const int G = out_size / 512;
  float* out = (float*)d_out;
  const int NB = (N + 127) / 128;          // gemm blocks
  const int NP = (G * 8 + 31) / 32;        // stat slots (32 finpool blocks/slot)
  const int NBKT = (N + 511) >> BSH;       // buckets (<=256 for N<=128K)

  char* p = (char*)d_ws;
  size_t off = 0;
  auto take = [&](size_t bytes) { void* r = p + off; off += (bytes + 255) & ~(size_t)255; return r; };
  __hip_bfloat16* hb0   = (__hip_bfloat16*)take((size_t)N * 128 * 2);
  __hip_bfloat16* hb1   = (__hip_bfloat16*)take((size_t)N * 128 * 2);
  __hip_bfloat16* Ysb   = (__hip_bfloat16*)take((size_t)N * 128 * 2);
  __hip_bfloat16* Ynb   = (__hip_bfloat16*)take((size_t)N * 128 * 2);
  __hip_bfloat16* Wst   = (__hip_bfloat16*)take((size_t)4 * 128 * 128 * 2);
  __hip_bfloat16* Wnt   = (__hip_bfloat16*)take((size_t)4 * 128 * 128 * 2);
  __hip_bfloat16* Wst2  = (__hip_bfloat16*)take((size_t)128 * 128 * 2);
  __hip_bfloat16* Wnt2  = (__hip_bfloat16*)take((size_t)128 * 128 * 2);
  float* partial        = (float*)take((size_t)NP * 256 * 4);
  float* ssbuf          = (float*)take((size_t)5 * 256 * 4);  // [l][sc|sh], l=0 identity
  float* beffS          = (float*)take((size_t)4 * 128 * 4);
  float* cNb            = (float*)take((size_t)4 * 128 * 4);
  uint2* binned  = (uint2*)take((size_t)E * 8);
  int*   csr_src = (int*)take((size_t)E * 4);
  int*   cnt     = (int*)take((size_t)N * 4);
  int*   rp      = (int*)take((size_t)(N + 1) * 4);
  int*   cursor  = (int*)take((size_t)N * 4);
  float* deg     = (float*)take((size_t)N * 4);
  int*   bs      = (int*)take(512);
  int*   gcnt    = (int*)take((size_t)G * 4);
  int*   gstart  = (int*)take((size_t)G * 4);
  int*   bktcnt  = (int*)take((size_t)NBKT * 4);
  int*   bbase   = (int*)take((size_t)(NBKT + 1) * 4);
  int*   bcur    = (int*)take((size_t)NBKT * 4);
  if (off > ws_size) return;

  hipMemsetAsync(bktcnt, 0, (size_t)NBKT * 4, stream);
  hipMemsetAsync(partial, 0, (size_t)NP * 256 * 4, stream);
  hipMemsetAsync(d_out, 0, (size_t)out_size * 4, stream);

  k_embed<<<(N * 16 + 255) / 256, 256, 0, stream>>>(in_feat, emb, (uint4*)hb0, N);
  k_wconv<<<(2 * 4 * 128 * 128 + 255) / 256, 256, 0, stream>>>(Wself, Wneigh, Wst, Wnt);
  k_gcount<<<1, 128, 0, stream>>>(gid, gcnt, gstart, N, G);

  int nbb = (E + BCHUNK - 1) / BCHUNK;
  k_bhist<<<nbb, 256, 0, stream>>>(dst, bktcnt, E, NBKT);
  k_bscan<<<1, 256, 0, stream>>>(bktcnt, bbase, bcur, E, NBKT);
  k_bin<<<nbb, 256, 0, stream>>>(src, dst, bcur, binned, E, NBKT);
  k_cnt<<<NBKT, 256, 0, stream>>>(binned, bbase, cnt, N);
  int nsb = (N + 1023) / 1024;
  k_scan1<<<nsb, 256, 0, stream>>>(cnt, rp, bs, N);
  k_scan2<<<1, 128, 0, stream>>>(bs, nsb);
  k_scan3<<<(N + 255) / 256, 256, 0, stream>>>(rp, bs, cnt, cursor, deg, N, E);
  k_place<<<NBKT, 256, 0, stream>>>(binned, bbase, rp, cursor, csr_src, N);
  k_prep<<<16, 256, 0, stream>>>(bvec, ssbuf, beffS, cNb,
                                 (const uint4*)Wst, (const uint4*)Wnt,
                                 (uint4*)Wst2, (uint4*)Wnt2);

  __hip_bfloat16* bufs[2] = {hb0, hb1};
  for (int l = 0; l < 4; ++l) {
    __hip_bfloat16* hin  = bufs[l & 1];
    __hip_bfloat16* hout = bufs[(l + 1) & 1];
    k_gemm2<<<NB, 256, 0, stream>>>(hin, Wst2, Wnt2, Ysb, Ynb, N);
    // hin is dead after gemm2 staged it -> reuse as aggY
    k_agg<<<AGG_BLOCKS, 256, 0, stream>>>((const uint4*)Ynb, rp, csr_src, deg,
                                          (uint4*)hin, N);
    k_finpool<<<G * 8, 256, 0, stream>>>((const uint4*)Ysb, (const uint4*)hin, cnt,
                                         beffS + l * 128, cNb + l * 128,
                                         prelu + l * 128, gstart, gcnt,
                                         (uint4*)hout, out, partial, l, N);
    k_bnfin<<<1, 1024, 0, stream>>>(partial, NP, gamma + l * 128, beta + l * 128,
                                    ssbuf + (l + 1) * 256,
                                    bvec + ((l + 1) & 3) * 128,
                                    Wself + ((l + 1) & 3) * 16384,
                                    Wneigh + ((l + 1) & 3) * 16384,
                                    Wst + ((l + 1) & 3) * 16384,
                                    Wnt + ((l + 1) & 3) * 16384,
                                    Wst2, Wnt2,
                                    beffS + ((l + 1) & 3) * 128,
                                    cNb + ((l + 1) & 3) * 128,
                                    (l < 3) ? 1 : 0, N);
  }
  k_div<<<(out_size + 255) / 256, 256, 0, stream>>>(out, gcnt, ssbuf, out_size);
}

// Round 15
// 579.766 us; speedup vs baseline: 1.2041x; 1.0088x over previous
//
#include <hip/hip_runtime.h>
#include <hip/hip_bf16.h>

// GraphSAGE 4-layer forward.
// R2-R5: bf16 activations; MFMA GEMM; BN folded forward; binned CSR build.
// R6-R13: GEMM staging wall ~711 GB/s regardless of schedule.
// R14: Y-space restructure (agg commutes with W): gemm2 stages ONE tile.
// R15: pure gather k_agg + finish fused into pool (k_finpool) -> 596us.
// R16: k_agg 16-edge pipeline (neutral -> gather is at memory roofline:
//     410MB logical / 59.4us = 6.9 TB/s effective, above 6.3 TB/s copy).
// R17: serial-tail cleanup -- W-prescale + partial-zero moved from 1-block
//     k_bnfin into 16-block k_wscale2; last-layer hbn store skipped.

#define EPS_BN 1e-5f
#define BSH 9                 // 512 nodes per bucket
#define BCHUNK 4096           // edges per k_bin block
#define PCAP 10240            // max edges per bucket for LDS staging (mean 8192)
#define AGG_BLOCKS 2048

typedef __attribute__((ext_vector_type(8))) short bf16x8;
typedef __attribute__((ext_vector_type(4))) float f32x4;
typedef __attribute__((address_space(1))) const void gconst_t;
typedef __attribute__((address_space(3))) void ldsv_t;

// ---------------- embedding gather -> bf16 h (16B/thread) --------------------
__global__ __launch_bounds__(256) void k_embed(const int* __restrict__ feat,
                                               const float* __restrict__ emb,
                                               uint4* __restrict__ hb4, int n) {
  int idx = blockIdx.x * 256 + threadIdx.x;   // one uint4 (8 channels) each
  if (idx < n * 16) {
    int i = idx >> 4, c8 = idx & 15;
    const float4* e = (const float4*)(emb + (size_t)feat[i] * 128 + c8 * 8);
    float4 f0 = e[0], f1 = e[1];
    __hip_bfloat162 p0 = __float22bfloat162_rn(make_float2(f0.x, f0.y));
    __hip_bfloat162 p1 = __float22bfloat162_rn(make_float2(f0.z, f0.w));
    __hip_bfloat162 p2 = __float22bfloat162_rn(make_float2(f1.x, f1.y));
    __hip_bfloat162 p3 = __float22bfloat162_rn(make_float2(f1.z, f1.w));
    uint4 o;
    o.x = *(unsigned int*)&p0; o.y = *(unsigned int*)&p1;
    o.z = *(unsigned int*)&p2; o.w = *(unsigned int*)&p3;
    hb4[idx] = o;
  }
}

// ------ W -> bf16, transposed, BOTH matrices in one dispatch -----------------
__global__ __launch_bounds__(256) void k_wconv(const float* __restrict__ Ws,
                                               const float* __restrict__ Wn,
                                               __hip_bfloat16* __restrict__ Wst,
                                               __hip_bfloat16* __restrict__ Wnt) {
  int idx = blockIdx.x * 256 + threadIdx.x;   // 0 .. 2*65536-1
  int half = idx >> 16, r = idx & 65535;
  int l = r >> 14, rr = r & 16383, nn = rr >> 7, kk = rr & 127;
  const float* W = half ? Wn : Ws;
  __hip_bfloat16* Wt = half ? Wnt : Wst;
  Wt[r] = __float2bfloat16(W[(l << 14) + kk * 128 + nn]);
}

// ---------------- per-graph node offsets via binary search (gid sorted) ------
__global__ void k_gcount(const int* __restrict__ gid, int* __restrict__ gcnt,
                         int* __restrict__ gstart, int n, int G) {
  int g = blockIdx.x * blockDim.x + threadIdx.x;
  if (g >= G) return;
  int lo0 = 0, hi = n;
  while (lo0 < hi) { int mid = (lo0 + hi) >> 1; if (gid[mid] < g) lo0 = mid + 1; else hi = mid; }
  int lo1 = lo0; hi = n;
  while (lo1 < hi) { int mid = (lo1 + hi) >> 1; if (gid[mid] < g + 1) lo1 = mid + 1; else hi = mid; }
  gstart[g] = lo0;
  gcnt[g] = lo1 - lo0;
}

// ---------------- bucket histogram over dst (LDS-staged) ---------------------
__global__ __launch_bounds__(256) void k_bhist(const int* __restrict__ dst,
                                               int* __restrict__ bktcnt, int m, int nbkt) {
  __shared__ int h[256];
  int t = threadIdx.x;
  h[t] = 0;
  __syncthreads();
#pragma unroll
  for (int k = 0; k < 4; ++k) {
    int idx = blockIdx.x * BCHUNK + k * 1024 + t * 4;
    if (idx + 4 <= m) {
      int4 d = *(const int4*)&dst[idx];
      atomicAdd(&h[d.x >> BSH], 1);
      atomicAdd(&h[d.y >> BSH], 1);
      atomicAdd(&h[d.z >> BSH], 1);
      atomicAdd(&h[d.w >> BSH], 1);
    } else {
      for (int e = idx; e < m && e < idx + 4; ++e) atomicAdd(&h[dst[e] >> BSH], 1);
    }
  }
  __syncthreads();
  for (int b = t; b < nbkt; b += 256)
    if (h[b]) atomicAdd(&bktcnt[b], h[b]);
}

// ---------------- scan bucket counts -> base & cursor ------------------------
__global__ void k_bscan(const int* __restrict__ bktcnt, int* __restrict__ bbase,
                        int* __restrict__ bcur, int m, int nbkt) {
  __shared__ int sh[256];
  int t = threadIdx.x;
  int v = (t < nbkt) ? bktcnt[t] : 0;
  sh[t] = v;
  __syncthreads();
  for (int o = 1; o < 256; o <<= 1) {
    int x = (t >= o) ? sh[t - o] : 0;
    __syncthreads();
    sh[t] += x;
    __syncthreads();
  }
  if (t < nbkt) { bbase[t] = sh[t] - v; bcur[t] = sh[t] - v; }
  if (t == 0) bbase[nbkt] = m;
}

// ---------------- bin edges by bucket (LDS counting sort, coalesced out) -----
__global__ __launch_bounds__(256) void k_bin(const int* __restrict__ src, const int* __restrict__ dst,
                                             int* __restrict__ bcur, uint2* __restrict__ binned,
                                             int m, int nbkt) {
  __shared__ uint2 st[BCHUNK];
  __shared__ int bcnt[256], boff[256], bres[256], wcur[256], ss[256];
  int t = threadIdx.x;
  int e0 = blockIdx.x * BCHUNK;
  int cn = min(BCHUNK, m - e0);
  int sv[16], dv[16];
  for (int b = t; b < 256; b += 256) bcnt[b] = 0;
  __syncthreads();
#pragma unroll
  for (int k = 0; k < 16; ++k) {
    int idx = e0 + k * 256 + t;
    if (idx < e0 + cn) {
      sv[k] = src[idx];
      dv[k] = dst[idx];
      atomicAdd(&bcnt[dv[k] >> BSH], 1);
    } else dv[k] = -1;
  }
  __syncthreads();
  int v = (t < nbkt) ? bcnt[t] : 0;
  ss[t] = v;
  __syncthreads();
  for (int o = 1; o < 256; o <<= 1) {
    int x = (t >= o) ? ss[t - o] : 0;
    __syncthreads();
    ss[t] += x;
    __syncthreads();
  }
  if (t < nbkt) {
    int ex = ss[t] - v;
    boff[t] = ex;
    wcur[t] = ex;
    if (v) bres[t] = atomicAdd(&bcur[t], v);
  }
  __syncthreads();
#pragma unroll
  for (int k = 0; k < 16; ++k) {
    if (dv[k] >= 0) {
      int b = dv[k] >> BSH;
      int p = atomicAdd(&wcur[b], 1);
      st[p] = make_uint2((unsigned)sv[k], (unsigned)dv[k]);
    }
  }
  __syncthreads();
  for (int j = t; j < cn; j += 256) {
    uint2 e = st[j];
    int b = (int)(e.y >> BSH);
    binned[(size_t)bres[b] + (j - boff[b])] = e;
  }
}

// ---------------- per-bucket node counts (LDS, coalesced cnt write) ----------
__global__ __launch_bounds__(256) void k_cnt(const uint2* __restrict__ binned,
                                             const int* __restrict__ bbase,
                                             int* __restrict__ cnt, int n) {
  __shared__ int h[512];
  int b = blockIdx.x, t = threadIdx.x;
  int base = b << BSH;
  int nn = min(512, n - base);
  h[t] = 0; h[t + 256] = 0;
  __syncthreads();
  int lo = bbase[b], hi = bbase[b + 1];
  for (int j = lo + t; j < hi; j += 256) atomicAdd(&h[(int)binned[j].y - base], 1);
  __syncthreads();
  if (t < nn) cnt[base + t] = h[t];
  if (t + 256 < nn) cnt[base + t + 256] = h[t + 256];
}

// ---------------- exclusive scan of cnt -> row_ptr (3 kernels) ---------------
__global__ __launch_bounds__(256) void k_scan1(const int* __restrict__ cnt,
                                               int* __restrict__ excl,
                                               int* __restrict__ blk_sums, int n) {
  __shared__ int sh[256];
  int t = threadIdx.x;
  int base = blockIdx.x * 1024 + t * 4;
  int4 v = {0, 0, 0, 0};
  if (base < n) v = *(const int4*)&cnt[base];
  int s = v.x + v.y + v.z + v.w;
  sh[t] = s;
  __syncthreads();
  for (int off = 1; off < 256; off <<= 1) {
    int x = (t >= off) ? sh[t - off] : 0;
    __syncthreads();
    sh[t] += x;
    __syncthreads();
  }
  int ex = sh[t] - s;
  if (t == 255) blk_sums[blockIdx.x] = sh[255];
  if (base < n) {
    excl[base]     = ex;
    excl[base + 1] = ex + v.x;
    excl[base + 2] = ex + v.x + v.y;
    excl[base + 3] = ex + v.x + v.y + v.z;
  }
}

__global__ void k_scan2(int* __restrict__ bs, int nb) {
  __shared__ int sh[128];
  int t = threadIdx.x;
  int v = (t < nb) ? bs[t] : 0;
  sh[t] = v;
  __syncthreads();
  for (int off = 1; off < 128; off <<= 1) {
    int x = (t >= off) ? sh[t - off] : 0;
    __syncthreads();
    sh[t] += x;
    __syncthreads();
  }
  if (t < nb) bs[t] = sh[t] - v;
}

__global__ __launch_bounds__(256) void k_scan3(int* __restrict__ rp, const int* __restrict__ bs,
                                               const int* __restrict__ cnt, int* __restrict__ cursor,
                                               float* __restrict__ deg, int n, int ne) {
  int i = blockIdx.x * 256 + threadIdx.x;
  if (i < n) {
    int r = rp[i] + bs[i >> 10];
    rp[i] = r;
    cursor[i] = r;
    int c = cnt[i];
    deg[i] = (float)(c > 0 ? c : 1);
  }
  if (i == 0) rp[n] = ne;
}

// ---------------- place edges into CSR (per-bucket LDS sort, coalesced) ------
__global__ __launch_bounds__(256) void k_place(const uint2* __restrict__ binned,
                                               const int* __restrict__ bbase,
                                               const int* __restrict__ rp,
                                               int* __restrict__ cursor,
                                               int* __restrict__ csr_src, int n) {
  int b = blockIdx.x, t = threadIdx.x;
  int base = b << BSH;
  int lo = bbase[b], hi = bbase[b + 1], m = hi - lo;
  if (m <= 0) return;
  if (m > PCAP) {                          // fallback: global-atomic scatter
    for (int j = lo + t; j < hi; j += 256) {
      uint2 e = binned[j];
      int p = atomicAdd(&cursor[(int)e.y], 1);
      csr_src[p] = (int)e.x;
    }
    return;
  }
  __shared__ int h[512], loff[512], wc[512], ss[256];
  __shared__ int stage[PCAP];
  h[t] = 0; h[t + 256] = 0;
  __syncthreads();
  for (int j = lo + t; j < hi; j += 256) atomicAdd(&h[(int)binned[j].y - base], 1);
  __syncthreads();
  int a0 = h[2 * t], a1 = h[2 * t + 1];
  int s = a0 + a1;
  ss[t] = s;
  __syncthreads();
  for (int o = 1; o < 256; o <<= 1) {
    int x = (t >= o) ? ss[t - o] : 0;
    __syncthreads();
    ss[t] += x;
    __syncthreads();
  }
  int ex = ss[t] - s;
  loff[2 * t] = ex; loff[2 * t + 1] = ex + a0;
  wc[2 * t] = ex;   wc[2 * t + 1] = ex + a0;
  __syncthreads();
  for (int j = lo + t; j < hi; j += 256) {
    uint2 e = binned[j];
    int p = atomicAdd(&wc[(int)e.y - base], 1);
    stage[p] = (int)e.x;
  }
  __syncthreads();
  int cb = rp[base];
  for (int j = t; j < m; j += 256) csr_src[cb + j] = stage[j];
}

// ----- init: identity BN, layer-0 beffS=b0, cN0=0, copy W0 -> Ws2/Wn2 --------
__global__ __launch_bounds__(256) void k_prep(const float* __restrict__ b0,
                                              float* __restrict__ ss0,
                                              float* __restrict__ beffS0,
                                              float* __restrict__ cN0,
                                              const uint4* __restrict__ Wst0,
                                              const uint4* __restrict__ Wnt0,
                                              uint4* __restrict__ Ws2,
                                              uint4* __restrict__ Wn2) {
  int id = blockIdx.x * 256 + threadIdx.x;     // 0..4095
  if (id < 128) {
    ss0[id] = 1.f; ss0[128 + id] = 0.f;
    beffS0[id] = b0[id]; cN0[id] = 0.f;
  }
  int half = id >> 11, ch = id & 2047;         // 2048 uint4 chunks each
  if (half) Wn2[ch] = Wnt0[ch]; else Ws2[ch] = Wst0[ch];
}

// ------- k_gemm2: Ys = hb@Ws2, Yn = hb@Wn2 (one staged A-tile) ---------------
__global__ __launch_bounds__(256) void k_gemm2(
    const __hip_bfloat16* __restrict__ hb,
    const __hip_bfloat16* __restrict__ Wst2, const __hip_bfloat16* __restrict__ Wnt2,
    __hip_bfloat16* __restrict__ Ys, __hip_bfloat16* __restrict__ Yn, int n) {
  __shared__ short Ah[128 * 128];
  int t = threadIdx.x;
  int row0 = blockIdx.x * 128;
  int w = t >> 6, lane = t & 63;

  // ---- async stage: 8 rounds, 16B/lane, LDS dest linear ----
#pragma unroll
  for (int rd = 0; rd < 8; ++rd) {
    int Gq = rd * 256 + w * 64 + lane;       // granule id 0..2047 (16B each)
    int r = Gq >> 4;                          // local row 0..127
    int gq = (Gq & 15) ^ (r & 7);             // pre-swizzled source granule
    int grow = row0 + r;
    grow = grow < n ? grow : n - 1;           // clamp: garbage rows never used
    const __hip_bfloat16* gs = hb + (size_t)grow * 128 + gq * 8;
    __builtin_amdgcn_global_load_lds((gconst_t*)gs,
        (ldsv_t*)&Ah[(rd * 256 + w * 64) * 8], 16, 0, 0);
  }
  asm volatile("s_waitcnt vmcnt(0)" ::: "memory");
  __syncthreads();

  int lr16 = lane & 15, hi = lane >> 4;
  const __hip_bfloat16* Bt[2] = {Wst2, Wnt2};
  __hip_bfloat16* Ot[2] = {Ys, Yn};
#pragma unroll
  for (int s = 0; s < 2; ++s) {
    const __hip_bfloat16* B = Bt[s];
    f32x4 acc[2][8];
#pragma unroll
    for (int fm = 0; fm < 2; ++fm)
#pragma unroll
      for (int fn = 0; fn < 8; ++fn) acc[fm][fn] = (f32x4){0.f, 0.f, 0.f, 0.f};
#pragma unroll
    for (int ks = 0; ks < 4; ++ks) {
      bf16x8 af[2], bfr[8];
#pragma unroll
      for (int fm = 0; fm < 2; ++fm) {
        int rl = w * 32 + fm * 16 + lr16;
        int gq = (ks * 4 + hi) ^ (lr16 & 7);
        af[fm] = *(const bf16x8*)&Ah[rl * 128 + gq * 8];
      }
#pragma unroll
      for (int fn = 0; fn < 8; ++fn)
        bfr[fn] = *(const bf16x8*)(B + (size_t)(fn * 16 + lr16) * 128 + ks * 32 + hi * 8);
#pragma unroll
      for (int fm = 0; fm < 2; ++fm)
#pragma unroll
        for (int fn = 0; fn < 8; ++fn)
          acc[fm][fn] = __builtin_amdgcn_mfma_f32_16x16x32_bf16(af[fm], bfr[fn], acc[fm][fn], 0, 0, 0);
    }
    // store this output (C/D: col = lane&15, row = 4*(lane>>4)+reg  [m89])
    __hip_bfloat16* O = Ot[s];
#pragma unroll
    for (int fm = 0; fm < 2; ++fm) {
      int rbase = row0 + w * 32 + fm * 16 + hi * 4;
#pragma unroll
      for (int fn = 0; fn < 8; ++fn) {
        int col = fn * 16 + lr16;
#pragma unroll
        for (int r = 0; r < 4; ++r) {
          int grow = rbase + r;
          if (grow < n) O[(size_t)grow * 128 + col] = __float2bfloat16(acc[fm][fn][r]);
        }
      }
    }
  }
}

// ------- k_agg: pure mean-gather of Yn rows -> aggY (bf16) -------------------
__device__ __forceinline__ void acc8(float* a, uint4 v) {
  float2 f;
  f = __bfloat1622float2(*(const __hip_bfloat162*)&v.x); a[0] += f.x; a[1] += f.y;
  f = __bfloat1622float2(*(const __hip_bfloat162*)&v.y); a[2] += f.x; a[3] += f.y;
  f = __bfloat1622float2(*(const __hip_bfloat162*)&v.z); a[4] += f.x; a[5] += f.y;
  f = __bfloat1622float2(*(const __hip_bfloat162*)&v.w); a[6] += f.x; a[7] += f.y;
}

__global__ __launch_bounds__(256) void k_agg(const uint4* __restrict__ yn4,
                                             const int* __restrict__ rp,
                                             const int* __restrict__ csr_src,
                                             const float* __restrict__ deg,
                                             uint4* __restrict__ aggY4, int n) {
  int lane = threadIdx.x & 63, wid = threadIdx.x >> 6;
  int g = lane >> 4, lr = lane & 15;
  for (int i = blockIdx.x * 4 + wid; i < n; i += gridDim.x * 4) {
    int beg = rp[i], end = rp[i + 1];
    float a[8];
#pragma unroll
    for (int c = 0; c < 8; ++c) a[c] = 0.f;
    int e = beg;
    for (; e + 16 <= end; e += 16) {      // 16 edges: 4 row-loads in flight
      int s0 = csr_src[e + g];
      int s1 = csr_src[e + 4 + g];
      int s2 = csr_src[e + 8 + g];
      int s3 = csr_src[e + 12 + g];
      uint4 v0 = yn4[(size_t)s0 * 16 + lr];
      uint4 v1 = yn4[(size_t)s1 * 16 + lr];
      uint4 v2 = yn4[(size_t)s2 * 16 + lr];
      uint4 v3 = yn4[(size_t)s3 * 16 + lr];
      acc8(a, v0);
      acc8(a, v1);
      acc8(a, v2);
      acc8(a, v3);
    }
    for (; e + 8 <= end; e += 8) {        // 8 edges: 2 in flight
      int s0 = csr_src[e + g];
      int s1 = csr_src[e + 4 + g];
      uint4 v0 = yn4[(size_t)s0 * 16 + lr];
      uint4 v1 = yn4[(size_t)s1 * 16 + lr];
      acc8(a, v0);
      acc8(a, v1);
    }
    for (; e + g < end; e += 4) {         // predicated 4-edge tail
      int s = csr_src[e + g];
      uint4 v = yn4[(size_t)s * 16 + lr];
      acc8(a, v);
    }
#pragma unroll
    for (int c = 0; c < 8; ++c) {         // combine the 4 groups
      a[c] += __shfl_xor(a[c], 16, 64);
      a[c] += __shfl_xor(a[c], 32, 64);
    }
    if (g == 0) {
      float invd = 1.0f / deg[i];
      __hip_bfloat162 p0 = __float22bfloat162_rn(make_float2(a[0] * invd, a[1] * invd));
      __hip_bfloat162 p1 = __float22bfloat162_rn(make_float2(a[2] * invd, a[3] * invd));
      __hip_bfloat162 p2 = __float22bfloat162_rn(make_float2(a[4] * invd, a[5] * invd));
      __hip_bfloat162 p3 = __float22bfloat162_rn(make_float2(a[6] * invd, a[7] * invd));
      uint4 o;
      o.x = *(unsigned int*)&p0; o.y = *(unsigned int*)&p1;
      o.z = *(unsigned int*)&p2; o.w = *(unsigned int*)&p3;
      aggY4[(size_t)i * 16 + lr] = o;
    }
  }
}

// ------- k_finpool: rst = PReLU(Ys + beffS + [cnt>0: aggY + cN]);  -----------
// writes next hb (unless last layer); ONE block reduction feeds per-graph
// pool AND BN stats (rows are gid-sorted; chunk lies in exactly one graph).
__global__ __launch_bounds__(256) void k_finpool(
    const uint4* __restrict__ ys4, const uint4* __restrict__ aggY4,
    const int* __restrict__ cnt,
    const float* __restrict__ beffS, const float* __restrict__ cN,
    const float* __restrict__ pw,
    const int* __restrict__ gstart, const int* __restrict__ gcnt,
    uint4* __restrict__ hbn4, float* __restrict__ out,
    float* __restrict__ partial, int l, int store_h, int n) {
  __shared__ float redS[4][128], redQ[4][128];
  int g = blockIdx.x >> 3, c = blockIdx.x & 7;
  int len = gcnt[g];
  int i0 = gstart[g] + ((len * c) >> 3);
  int i1 = gstart[g] + ((len * (c + 1)) >> 3);
  if (i0 >= i1) return;                       // block-uniform
  int t = threadIdx.x, w = t >> 6, lane = t & 63;
  int gi = lane >> 4, lr = lane & 15;
  float bS[8], cn8[8], pw8[8], S[8], Q[8];
#pragma unroll
  for (int k = 0; k < 8; ++k) {
    bS[k] = beffS[lr * 8 + k];
    cn8[k] = cN[lr * 8 + k];
    pw8[k] = pw[lr * 8 + k];
    S[k] = 0.f; Q[k] = 0.f;
  }
  for (int r = i0 + w * 4 + gi; r < i1; r += 16) {   // 16 rows in flight
    uint4 ys = ys4[(size_t)r * 16 + lr];
    uint4 ag = aggY4[(size_t)r * 16 + lr];
    bool has = cnt[r] > 0;
    float y[8], a[8];
    float2 f;
    f = __bfloat1622float2(*(const __hip_bfloat162*)&ys.x); y[0] = f.x; y[1] = f.y;
    f = __bfloat1622float2(*(const __hip_bfloat162*)&ys.y); y[2] = f.x; y[3] = f.y;
    f = __bfloat1622float2(*(const __hip_bfloat162*)&ys.z); y[4] = f.x; y[5] = f.y;
    f = __bfloat1622float2(*(const __hip_bfloat162*)&ys.w); y[6] = f.x; y[7] = f.y;
    f = __bfloat1622float2(*(const __hip_bfloat162*)&ag.x); a[0] = f.x; a[1] = f.y;
    f = __bfloat1622float2(*(const __hip_bfloat162*)&ag.y); a[2] = f.x; a[3] = f.y;
    f = __bfloat1622float2(*(const __hip_bfloat162*)&ag.z); a[4] = f.x; a[5] = f.y;
    f = __bfloat1622float2(*(const __hip_bfloat162*)&ag.w); a[6] = f.x; a[7] = f.y;
    float x[8];
#pragma unroll
    for (int k = 0; k < 8; ++k) {
      float xx = y[k] + bS[k];
      if (has) xx += a[k] + cn8[k];
      xx = xx > 0.f ? xx : pw8[k] * xx;
      S[k] += xx; Q[k] += xx * xx;
      x[k] = xx;
    }
    if (store_h) {
      __hip_bfloat162 p0 = __float22bfloat162_rn(make_float2(x[0], x[1]));
      __hip_bfloat162 p1 = __float22bfloat162_rn(make_float2(x[2], x[3]));
      __hip_bfloat162 p2 = __float22bfloat162_rn(make_float2(x[4], x[5]));
      __hip_bfloat162 p3 = __float22bfloat162_rn(make_float2(x[6], x[7]));
      uint4 o;
      o.x = *(unsigned int*)&p0; o.y = *(unsigned int*)&p1;
      o.z = *(unsigned int*)&p2; o.w = *(unsigned int*)&p3;
      hbn4[(size_t)r * 16 + lr] = o;
    }
  }
#pragma unroll
  for (int k = 0; k < 8; ++k) {                      // combine 4 groups in wave
    S[k] += __shfl_xor(S[k], 16, 64);
    S[k] += __shfl_xor(S[k], 32, 64);
    Q[k] += __shfl_xor(Q[k], 16, 64);
    Q[k] += __shfl_xor(Q[k], 32, 64);
  }
  if (gi == 0) {
#pragma unroll
    for (int k = 0; k < 8; ++k) {
      redS[w][lr * 8 + k] = S[k];
      redQ[w][lr * 8 + k] = Q[k];
    }
  }
  __syncthreads();
  if (t < 128) {
    float s = redS[0][t] + redS[1][t] + redS[2][t] + redS[3][t];
    float q = redQ[0][t] + redQ[1][t] + redQ[2][t] + redQ[3][t];
    atomicAdd(&out[(size_t)g * 512 + l * 128 + t], s);
    float* pp = partial + (size_t)(blockIdx.x >> 5) * 256;
    atomicAdd(&pp[t], s);
    atomicAdd(&pp[128 + t], q);
  }
}

// ---- bnfin: stats -> BN affine + next-layer beffS/cN (coalesced fp32 W) -----
__global__ __launch_bounds__(1024) void k_bnfin(const float* __restrict__ partial, int nb,
                                                const float* __restrict__ gamma,
                                                const float* __restrict__ beta,
                                                float* __restrict__ ss,
                                                const float* __restrict__ bias_next,
                                                const float* __restrict__ Wsf_next,
                                                const float* __restrict__ Wnf_next,
                                                float* __restrict__ beffS_next,
                                                float* __restrict__ cN_next,
                                                int has_next, int n) {
  __shared__ float red[4][256];
  __shared__ float shv[128];
  __shared__ float bredS[8][128], bredN[8][128];
  int t = threadIdx.x, c = t & 255, part = t >> 8;
  float s = 0.f;
  for (int b = part; b < nb; b += 4) s += partial[(size_t)b * 256 + c];
  red[part][c] = s;
  __syncthreads();
  if (part == 0) red[0][c] = red[0][c] + red[1][c] + red[2][c] + red[3][c];
  __syncthreads();
  if (t < 128) {
    float inv_n = 1.0f / (float)n;
    float mu = red[0][t] * inv_n;
    float var = red[0][128 + t] * inv_n - mu * mu;
    float sc = rsqrtf(var + EPS_BN) * gamma[t];
    float sh = beta[t] - mu * sc;
    ss[t] = sc;
    ss[128 + t] = sh;
    shv[t] = sh;
  }
  __syncthreads();
  if (has_next) {
    int cc = t & 127, kg = t >> 7;       // 8 k-groups x 128 channels
    float aS = 0.f, aN = 0.f;
#pragma unroll
    for (int k = kg * 16; k < kg * 16 + 16; ++k) {
      float sh = shv[k];
      aS += sh * Wsf_next[k * 128 + cc];
      aN += sh * Wnf_next[k * 128 + cc];
    }
    bredS[kg][cc] = aS;
    bredN[kg][cc] = aN;
    __syncthreads();
    if (t < 128) {
      float rS = bias_next[t], rN = 0.f;
#pragma unroll
      for (int kg2 = 0; kg2 < 8; ++kg2) { rS += bredS[kg2][t]; rN += bredN[kg2][t]; }
      beffS_next[t] = rS;
      cN_next[t] = rN;
    }
  }
}

// ---- wscale2: prescale next-layer Wt by sc[k] (16 blocks) + zero partial ----
__global__ __launch_bounds__(256) void k_wscale2(const float* __restrict__ ss_next,
                                                 const uint4* __restrict__ Wst_next,
                                                 const uint4* __restrict__ Wnt_next,
                                                 uint4* __restrict__ Ws2,
                                                 uint4* __restrict__ Wn2,
                                                 float* __restrict__ partial, int npw) {
  int id = blockIdx.x * 256 + threadIdx.x;     // 0..4095
  int half = id >> 11, ch = id & 2047;         // uint4 chunk within 16384 el
  const uint4* Wsrc = half ? Wnt_next : Wst_next;
  uint4* Wdst = half ? Wn2 : Ws2;
  uint4 v = Wsrc[ch];
  int k0 = (ch * 8) & 127;
  __hip_bfloat162* pv = (__hip_bfloat162*)&v;
#pragma unroll
  for (int j = 0; j < 4; ++j) {
    float2 f = __bfloat1622float2(pv[j]);
    f.x *= ss_next[k0 + 2 * j]; f.y *= ss_next[k0 + 2 * j + 1];
    pv[j] = __float22bfloat162_rn(f);
  }
  Wdst[ch] = v;
  for (int i = id; i < npw; i += 4096) partial[i] = 0.f;
}

// ------------- finalize: mean + BN affine per layer section ------------------
__global__ __launch_bounds__(256) void k_div(float* __restrict__ out, const int* __restrict__ gcnt,
                                             const float* __restrict__ ssbuf, int m) {
  int i = blockIdx.x * 256 + threadIdx.x;
  if (i < m) {
    int g = i >> 9;
    int lc = i & 511;
    int l = lc >> 7, c = lc & 127;
    const float* ss = ssbuf + (l + 1) * 256;
    int cn = gcnt[g];
    out[i] = (cn > 0) ? (out[i] / (float)cn) * ss[c] + ss[128 + c] : 0.f;
  }
}

extern "C" void kernel_launch(void* const* d_in, const int* in_sizes, int n_in,
                              void* d_out, int out_size, void* d_ws, size_t ws_size,
                              hipStream_t stream) {
  const int*   in_feat = (const int*)d_in[0];
  const int*   src     = (const int*)d_in[1];
  const int*   dst     = (const int*)d_in[2];
  const int*   gid     = (const int*)d_in[3];
  const float* emb     = (const float*)d_in[4];
  const float* Wself   = (const float*)d_in[5];
  const float* Wneigh  = (const float*)d_in[6];
  const float* bvec    = (const float*)d_in[7];
  const float* gamma   = (const float*)d_in[8];
  const float* beta    = (const float*)d_in[9];
  const float* prelu   = (const float*)d_in[10];
  const int N = in_sizes[0];
  const int E = in_sizes[1];
  const int G = out_size / 512;
  float* out = (float*)d_out;
  const int NB = (N + 127) / 128;          // gemm blocks
  const int NP = (G * 8 + 31) / 32;        // stat slots (32 finpool blocks/slot)
  const int NBKT = (N + 511) >> BSH;       // buckets (<=256 for N<=128K)

  char* p = (char*)d_ws;
  size_t off = 0;
  auto take = [&](size_t bytes) { void* r = p + off; off += (bytes + 255) & ~(size_t)255; return r; };
  __hip_bfloat16* hb0   = (__hip_bfloat16*)take((size_t)N * 128 * 2);
  __hip_bfloat16* hb1   = (__hip_bfloat16*)take((size_t)N * 128 * 2);
  __hip_bfloat16* Ysb   = (__hip_bfloat16*)take((size_t)N * 128 * 2);
  __hip_bfloat16* Ynb   = (__hip_bfloat16*)take((size_t)N * 128 * 2);
  __hip_bfloat16* Wst   = (__hip_bfloat16*)take((size_t)4 * 128 * 128 * 2);
  __hip_bfloat16* Wnt   = (__hip_bfloat16*)take((size_t)4 * 128 * 128 * 2);
  __hip_bfloat16* Wst2  = (__hip_bfloat16*)take((size_t)128 * 128 * 2);
  __hip_bfloat16* Wnt2  = (__hip_bfloat16*)take((size_t)128 * 128 * 2);
  float* partial        = (float*)take((size_t)NP * 256 * 4);
  float* ssbuf          = (float*)take((size_t)5 * 256 * 4);  // [l][sc|sh], l=0 identity
  float* beffS          = (float*)take((size_t)4 * 128 * 4);
  float* cNb            = (float*)take((size_t)4 * 128 * 4);
  uint2* binned  = (uint2*)take((size_t)E * 8);
  int*   csr_src = (int*)take((size_t)E * 4);
  int*   cnt     = (int*)take((size_t)N * 4);
  int*   rp      = (int*)take((size_t)(N + 1) * 4);
  int*   cursor  = (int*)take((size_t)N * 4);
  float* deg     = (float*)take((size_t)N * 4);
  int*   bs      = (int*)take(512);
  int*   gcnt    = (int*)take((size_t)G * 4);
  int*   gstart  = (int*)take((size_t)G * 4);
  int*   bktcnt  = (int*)take((size_t)NBKT * 4);
  int*   bbase   = (int*)take((size_t)(NBKT + 1) * 4);
  int*   bcur    = (int*)take((size_t)NBKT * 4);
  if (off > ws_size) return;

  hipMemsetAsync(bktcnt, 0, (size_t)NBKT * 4, stream);
  hipMemsetAsync(partial, 0, (size_t)NP * 256 * 4, stream);
  hipMemsetAsync(d_out, 0, (size_t)out_size * 4, stream);

  k_embed<<<(N * 16 + 255) / 256, 256, 0, stream>>>(in_feat, emb, (uint4*)hb0, N);
  k_wconv<<<(2 * 4 * 128 * 128 + 255) / 256, 256, 0, stream>>>(Wself, Wneigh, Wst, Wnt);
  k_gcount<<<1, 128, 0, stream>>>(gid, gcnt, gstart, N, G);

  int nbb = (E + BCHUNK - 1) / BCHUNK;
  k_bhist<<<nbb, 256, 0, stream>>>(dst, bktcnt, E, NBKT);
  k_bscan<<<1, 256, 0, stream>>>(bktcnt, bbase, bcur, E, NBKT);
  k_bin<<<nbb, 256, 0, stream>>>(src, dst, bcur, binned, E, NBKT);
  k_cnt<<<NBKT, 256, 0, stream>>>(binned, bbase, cnt, N);
  int nsb = (N + 1023) / 1024;
  k_scan1<<<nsb, 256, 0, stream>>>(cnt, rp, bs, N);
  k_scan2<<<1, 128, 0, stream>>>(bs, nsb);
  k_scan3<<<(N + 255) / 256, 256, 0, stream>>>(rp, bs, cnt, cursor, deg, N, E);
  k_place<<<NBKT, 256, 0, stream>>>(binned, bbase, rp, cursor, csr_src, N);
  k_prep<<<16, 256, 0, stream>>>(bvec, ssbuf, beffS, cNb,
                                 (const uint4*)Wst, (const uint4*)Wnt,
                                 (uint4*)Wst2, (uint4*)Wnt2);

  __hip_bfloat16* bufs[2] = {hb0, hb1};
  for (int l = 0; l < 4; ++l) {
    __hip_bfloat16* hin  = bufs[l & 1];
    __hip_bfloat16* hout = bufs[(l + 1) & 1];
    int has_next = (l < 3) ? 1 : 0;
    k_gemm2<<<NB, 256, 0, stream>>>(hin, Wst2, Wnt2, Ysb, Ynb, N);
    // hin is dead after gemm2 staged it -> reuse as aggY
    k_agg<<<AGG_BLOCKS, 256, 0, stream>>>((const uint4*)Ynb, rp, csr_src, deg,
                                          (uint4*)hin, N);
    k_finpool<<<G * 8, 256, 0, stream>>>((const uint4*)Ysb, (const uint4*)hin, cnt,
                                         beffS + l * 128, cNb + l * 128,
                                         prelu + l * 128, gstart, gcnt,
                                         (uint4*)hout, out, partial, l, has_next, N);
    k_bnfin<<<1, 1024, 0, stream>>>(partial, NP, gamma + l * 128, beta + l * 128,
                                    ssbuf + (l + 1) * 256,
                                    bvec + ((l + 1) & 3) * 128,
                                    Wself + ((l + 1) & 3) * 16384,
                                    Wneigh + ((l + 1) & 3) * 16384,
                                    beffS + ((l + 1) & 3) * 128,
                                    cNb + ((l + 1) & 3) * 128,
                                    has_next, N);
    if (has_next)
      k_wscale2<<<16, 256, 0, stream>>>(ssbuf + (l + 1) * 256,
                                        (const uint4*)(Wst + (l + 1) * 16384),
                                        (const uint4*)(Wnt + (l + 1) * 16384),
                                        (uint4*)Wst2, (uint4*)Wnt2,
                                        partial, NP * 256);
  }
  k_div<<<(out_size + 255) / 256, 256, 0, stream>>>(out, gcnt, ssbuf, out_size);
}